// Round 1
// baseline (259.102 us; speedup 1.0000x reference)
//
#include <hip/hip_runtime.h>
#include <hip/hip_bf16.h>
#include <stdint.h>

// Problem sizes (fixed)
#define MROWS 4096   // batch B
#define LFULL 4096   // L
#define NHALF 2048   // N = L/2
#define HDIM  2048   // H

typedef __bf16 bf16x8 __attribute__((ext_vector_type(8)));
typedef float  f32x4  __attribute__((ext_vector_type(4)));
typedef unsigned short u16x8 __attribute__((ext_vector_type(8)));

__device__ __forceinline__ unsigned short f2bf(float f) {
    __hip_bfloat16 h = __float2bfloat16(f);
    return __builtin_bit_cast(unsigned short, h);
}
__device__ __forceinline__ float bf2f(unsigned short u) {
    return __builtin_bit_cast(float, (uint32_t)u << 16);
}
__device__ __forceinline__ float fast_tanh(float x) {
    float ax = fabsf(x);
    float e  = __expf(-2.0f * ax);          // in (0,1]
    float t  = (1.0f - e) / (1.0f + e);     // tanh(|x|), stable
    return copysignf(t, x);
}

__device__ __forceinline__ void gload_lds16(const void* g, void* l) {
    __builtin_amdgcn_global_load_lds(
        (const __attribute__((address_space(1))) uint32_t*)g,
        (__attribute__((address_space(3))) uint32_t*)l,
        16, 0, 0);
}

// ---------------------------------------------------------------------------
// Cast x even columns -> bf16 x_m (MROWS x NHALF)
// ---------------------------------------------------------------------------
__global__ __launch_bounds__(256)
void cast_x_kernel(const float* __restrict__ x, __hip_bfloat16* __restrict__ xm)
{
    size_t t = (size_t)blockIdx.x * 256 + threadIdx.x;   // 4096*256 threads
    size_t r = t >> 8;
    int    c = (int)(t & 255);                           // 8 outputs per thread
    const float4* xp = (const float4*)(x + r * LFULL + (size_t)c * 16);
    float4 a = xp[0], b = xp[1], d = xp[2], e = xp[3];
    u16x8 v;
    v[0] = f2bf(a.x); v[1] = f2bf(a.z);
    v[2] = f2bf(b.x); v[3] = f2bf(b.z);
    v[4] = f2bf(d.x); v[5] = f2bf(d.z);
    v[6] = f2bf(e.x); v[7] = f2bf(e.z);
    *(u16x8*)(xm + r * NHALF + (size_t)c * 8) = v;
}

// ---------------------------------------------------------------------------
// Transpose + cast: W (K x N, f32) -> WT (N x K, bf16)
// ---------------------------------------------------------------------------
__global__ __launch_bounds__(256)
void transpose_cast_kernel(const float* __restrict__ W, __hip_bfloat16* __restrict__ WT,
                           int K, int N)
{
    __shared__ unsigned short lds[64][66];   // +2 pad: conflict-free column reads
    const int t  = threadIdx.x;
    const int k0 = blockIdx.y * 64;
    const int n0 = blockIdx.x * 64;

    #pragma unroll
    for (int it = 0; it < 4; ++it) {
        int kl = it * 16 + (t >> 4);
        int nl = (t & 15) * 4;
        float4 v = *(const float4*)(W + (size_t)(k0 + kl) * N + n0 + nl);
        lds[kl][nl + 0] = f2bf(v.x);
        lds[kl][nl + 1] = f2bf(v.y);
        lds[kl][nl + 2] = f2bf(v.z);
        lds[kl][nl + 3] = f2bf(v.w);
    }
    __syncthreads();

    int nl = t >> 2;
    int kc = (t & 3) * 16;
    unsigned short tmp[16];
    #pragma unroll
    for (int j = 0; j < 16; ++j) tmp[j] = lds[kc + j][nl];
    u16x8* dst = (u16x8*)(WT + (size_t)(n0 + nl) * K + k0 + kc);
    dst[0] = *(u16x8*)&tmp[0];
    dst[1] = *(u16x8*)&tmp[8];
}

// ---------------------------------------------------------------------------
// GEMM: C = act(A @ B + bias), A: MxK bf16 row-major, BT: Nout x K bf16
// 128x128 tile, BK=64, 4 waves (2x2), 16x16x32 bf16 MFMA. m97 structure.
// ---------------------------------------------------------------------------
template<bool RELU>
__global__ __launch_bounds__(256, 2)
void gemm_bt(const __hip_bfloat16* __restrict__ A,
             const __hip_bfloat16* __restrict__ BT,
             const float* __restrict__ bias,
             __hip_bfloat16* __restrict__ C,
             int M, int K, int Nout)
{
    __shared__ __align__(16) __hip_bfloat16 As[128][64];
    __shared__ __align__(16) __hip_bfloat16 Bs[128][64];

    const int tid  = threadIdx.x;
    const int wave = tid >> 6;
    const int lane = tid & 63;
    const int bm = blockIdx.y;
    const int bn = blockIdx.x;
    const int wm = wave >> 1, wn = wave & 1;

    // staging pattern: per wave, per iter: 32-row stripe, lane -> (row, col8)
    const int srow = wave * 8 + (lane >> 3);
    const int scol = (lane & 7) * 8;

    const __hip_bfloat16* Ap = A  + (size_t)(bm * 128 + srow) * K + scol;
    const __hip_bfloat16* Bp = BT + (size_t)(bn * 128 + srow) * K + scol;

    f32x4 acc[4][4] = {};

    const int l15 = lane & 15;
    const int lhi = lane >> 4;

    for (int k0 = 0; k0 < K; k0 += 64) {
        #pragma unroll
        for (int it = 0; it < 4; ++it) {
            gload_lds16(Ap + (size_t)(it * 32) * K + k0, &As[it * 32 + srow][scol]);
            gload_lds16(Bp + (size_t)(it * 32) * K + k0, &Bs[it * 32 + srow][scol]);
        }
        __syncthreads();
        #pragma unroll
        for (int kk = 0; kk < 2; ++kk) {
            bf16x8 af[4], bfv[4];
            #pragma unroll
            for (int m = 0; m < 4; ++m)
                af[m] = *(const bf16x8*)&As[wm * 64 + m * 16 + l15][kk * 32 + lhi * 8];
            #pragma unroll
            for (int n = 0; n < 4; ++n)
                bfv[n] = *(const bf16x8*)&Bs[wn * 64 + n * 16 + l15][kk * 32 + lhi * 8];
            #pragma unroll
            for (int m = 0; m < 4; ++m)
                #pragma unroll
                for (int n = 0; n < 4; ++n)
                    acc[m][n] = __builtin_amdgcn_mfma_f32_16x16x32_bf16(
                        af[m], bfv[n], acc[m][n], 0, 0, 0);
        }
        __syncthreads();
    }

    // C/D layout: col = lane&15, row = (lane>>4)*4 + reg
    const int col0 = bn * 128 + wn * 64 + l15;
    const int row0 = bm * 128 + wm * 64 + lhi * 4;
    #pragma unroll
    for (int m = 0; m < 4; ++m) {
        #pragma unroll
        for (int n = 0; n < 4; ++n) {
            int col = col0 + n * 16;
            float bv = bias[col];
            #pragma unroll
            for (int r = 0; r < 4; ++r) {
                int row = row0 + m * 16 + r;
                float v = acc[m][n][r] + bv;
                if (RELU) v = (v > 0.0f) ? v : 0.2f * v;
                C[(size_t)row * Nout + col] = __float2bfloat16(v);
            }
        }
    }
}

// ---------------------------------------------------------------------------
// Epilogue: s/t split, y assembly, per-row log_det
// ---------------------------------------------------------------------------
__global__ __launch_bounds__(256)
void epilogue_kernel(const float* __restrict__ x,
                     const __hip_bfloat16* __restrict__ outb,
                     float* __restrict__ y, float* __restrict__ ld)
{
    const int i = blockIdx.x;
    const int t = threadIdx.x;
    const __hip_bfloat16* orow = outb + (size_t)i * LFULL;
    const float* xrow = x + (size_t)i * LFULL;
    float* yrow = y + (size_t)i * LFULL;

    const int j0 = t * 8;                          // 8 (s,t) pairs per thread
    u16x8 sv = *(const u16x8*)(orow + j0);
    u16x8 tv = *(const u16x8*)(orow + NHALF + j0);

    float part = 0.0f;
    #pragma unroll
    for (int u = 0; u < 8; u += 2) {
        float4 xv = *(const float4*)(xrow + 2 * (j0 + u));
        float s0 = bf2f(sv[u]),     s1 = bf2f(sv[u + 1]);
        float t0 = bf2f(tv[u]),     t1 = bf2f(tv[u + 1]);
        float a0 = 2.0f * fast_tanh(s0);
        float a1 = 2.0f * fast_tanh(s1);
        part += a0 + a1;
        float4 yv;
        yv.x = xv.x;  yv.y = xv.y * __expf(a0) + t0;
        yv.z = xv.z;  yv.w = xv.w * __expf(a1) + t1;
        *(float4*)(yrow + 2 * (j0 + u)) = yv;
    }

    // block reduction (4 waves)
    #pragma unroll
    for (int off = 32; off; off >>= 1) part += __shfl_down(part, off, 64);
    __shared__ float red[4];
    if ((t & 63) == 0) red[t >> 6] = part;
    __syncthreads();
    if (t == 0) ld[i] = red[0] + red[1] + red[2] + red[3];
}

// ---------------------------------------------------------------------------
extern "C" void kernel_launch(void* const* d_in, const int* in_sizes, int n_in,
                              void* d_out, int out_size, void* d_ws, size_t ws_size,
                              hipStream_t stream)
{
    const float* x  = (const float*)d_in[0];
    const float* W1 = (const float*)d_in[1];
    const float* b1 = (const float*)d_in[2];
    const float* W2 = (const float*)d_in[3];
    const float* b2 = (const float*)d_in[4];
    const float* W3 = (const float*)d_in[5];
    const float* b3 = (const float*)d_in[6];
    // d_in[7]/d_in[8]: idx arrays — fixed even/odd pattern, unused

    char* ws = (char*)d_ws;
    const size_t MB = 1u << 20;
    __hip_bfloat16* W3T  = (__hip_bfloat16*)(ws);              // 16 MB: 4096x2048
    __hip_bfloat16* h2   = (__hip_bfloat16*)(ws + 16 * MB);    // 16 MB: 4096x2048
    __hip_bfloat16* xmb  = (__hip_bfloat16*)(ws + 32 * MB);    // 16 MB: 4096x2048
    __hip_bfloat16* W1T  = (__hip_bfloat16*)(ws + 48 * MB);    //  8 MB: 2048x2048
    __hip_bfloat16* W2T  = (__hip_bfloat16*)(ws + 56 * MB);    //  8 MB: 2048x2048
    __hip_bfloat16* h1   = (__hip_bfloat16*)(ws + 64 * MB);    // 16 MB: 4096x2048
    __hip_bfloat16* outb = (__hip_bfloat16*)(ws + 32 * MB);    // 32 MB: 4096x4096
                                                               // (overlays xmb/W1T/W2T: dead by GEMM3)
    float* y  = (float*)d_out;
    float* ld = y + (size_t)MROWS * LFULL;

    cast_x_kernel<<<4096, 256, 0, stream>>>(x, xmb);
    transpose_cast_kernel<<<dim3(32, 32), 256, 0, stream>>>(W1, W1T, HDIM, HDIM);
    transpose_cast_kernel<<<dim3(32, 32), 256, 0, stream>>>(W2, W2T, HDIM, HDIM);
    transpose_cast_kernel<<<dim3(64, 32), 256, 0, stream>>>(W3, W3T, HDIM, LFULL);

    gemm_bt<true ><<<dim3(16, 32), 256, 0, stream>>>(xmb, W1T, b1, h1, MROWS, HDIM, HDIM);
    gemm_bt<true ><<<dim3(16, 32), 256, 0, stream>>>(h1,  W2T, b2, h2, MROWS, HDIM, HDIM);
    gemm_bt<false><<<dim3(32, 32), 256, 0, stream>>>(h2,  W3T, b3, outb, MROWS, HDIM, LFULL);

    epilogue_kernel<<<4096, 256, 0, stream>>>(x, outb, y, ld);
}

// Round 2
// 230.224 us; speedup vs baseline: 1.1254x; 1.1254x over previous
//
#include <hip/hip_runtime.h>
#include <hip/hip_bf16.h>
#include <stdint.h>

// Problem sizes (fixed)
#define MROWS 4096   // batch B
#define LFULL 4096   // L
#define NHALF 2048   // N = L/2
#define HDIM  2048   // H

typedef __bf16 bf16x8 __attribute__((ext_vector_type(8)));
typedef float  f32x4  __attribute__((ext_vector_type(4)));
typedef unsigned short u16x8 __attribute__((ext_vector_type(8)));

__device__ __forceinline__ unsigned short f2bf(float f) {
    __hip_bfloat16 h = __float2bfloat16(f);
    return __builtin_bit_cast(unsigned short, h);
}
__device__ __forceinline__ float bf2f(unsigned short u) {
    return __builtin_bit_cast(float, (uint32_t)u << 16);
}
__device__ __forceinline__ float fast_tanh(float x) {
    float ax = fabsf(x);
    float e  = __expf(-2.0f * ax);
    float t  = (1.0f - e) / (1.0f + e);
    return copysignf(t, x);
}

__device__ __forceinline__ void gload_lds16(const void* g, void* l) {
    __builtin_amdgcn_global_load_lds(
        (const __attribute__((address_space(1))) uint32_t*)g,
        (__attribute__((address_space(3))) uint32_t*)l,
        16, 0, 0);
}

#define WAIT_LGKM0 do { asm volatile("s_waitcnt lgkmcnt(0)" ::: "memory"); __builtin_amdgcn_sched_barrier(0); } while (0)
#define BARRIER    do { __builtin_amdgcn_s_barrier(); __builtin_amdgcn_sched_barrier(0); } while (0)

// Stage one 64-row x 64-col bf16 segment: 512 threads x 16B, linear LDS dest,
// XOR-swizzled (st_16x32) global source chunk.
__device__ __forceinline__ void stage64(const __hip_bfloat16* g, int ldK, char* ldsHalf, int tid) {
    int r = tid >> 3, c = tid & 7;
    int sc = c ^ (((r >> 2) & 1) << 1);          // byte bit5 <- row bit2
    gload_lds16(g + (size_t)r * ldK + sc * 8, ldsHalf + r * 128 + c * 16);
}

// Swizzled ds_read of a 16B MFMA fragment slice. row in tile, colByte in [0,128)
__device__ __forceinline__ bf16x8 ldsRead(const char* tileBase, int row, int colByte) {
    int off = row * 128 + colByte;
    off ^= ((off >> 9) & 1) << 5;                // st_16x32 swizzle
    return *(const bf16x8*)(tileBase + off);
}

// ---------------------------------------------------------------------------
// Cast x even columns -> bf16 x_m (MROWS x NHALF)
// ---------------------------------------------------------------------------
__global__ __launch_bounds__(256)
void cast_x_kernel(const float* __restrict__ x, __hip_bfloat16* __restrict__ xm)
{
    size_t t = (size_t)blockIdx.x * 256 + threadIdx.x;
    size_t r = t >> 8;
    int    c = (int)(t & 255);
    const float4* xp = (const float4*)(x + r * LFULL + (size_t)c * 16);
    float4 a = xp[0], b = xp[1], d = xp[2], e = xp[3];
    u16x8 v;
    v[0] = f2bf(a.x); v[1] = f2bf(a.z);
    v[2] = f2bf(b.x); v[3] = f2bf(b.z);
    v[4] = f2bf(d.x); v[5] = f2bf(d.z);
    v[6] = f2bf(e.x); v[7] = f2bf(e.z);
    *(u16x8*)(xm + r * NHALF + (size_t)c * 8) = v;
}

// ---------------------------------------------------------------------------
// Transpose + cast: W (K x N, f32) -> WT (N x K, bf16)
// ---------------------------------------------------------------------------
__global__ __launch_bounds__(256)
void transpose_cast_kernel(const float* __restrict__ W, __hip_bfloat16* __restrict__ WT,
                           int K, int N)
{
    __shared__ unsigned short lds[64][66];
    const int t  = threadIdx.x;
    const int k0 = blockIdx.y * 64;
    const int n0 = blockIdx.x * 64;

    #pragma unroll
    for (int it = 0; it < 4; ++it) {
        int kl = it * 16 + (t >> 4);
        int nl = (t & 15) * 4;
        float4 v = *(const float4*)(W + (size_t)(k0 + kl) * N + n0 + nl);
        lds[kl][nl + 0] = f2bf(v.x);
        lds[kl][nl + 1] = f2bf(v.y);
        lds[kl][nl + 2] = f2bf(v.z);
        lds[kl][nl + 3] = f2bf(v.w);
    }
    __syncthreads();

    int nl = t >> 2;
    int kc = (t & 3) * 16;
    unsigned short tmp[16];
    #pragma unroll
    for (int j = 0; j < 16; ++j) tmp[j] = lds[kc + j][nl];
    u16x8* dst = (u16x8*)(WT + (size_t)(n0 + nl) * K + k0 + kc);
    dst[0] = *(u16x8*)&tmp[0];
    dst[1] = *(u16x8*)&tmp[8];
}

// ---------------------------------------------------------------------------
// 8-phase 256-class GEMM: C = act(A @ B + bias)
// A: MxK bf16 row-major; BT: Nout x K bf16 (B transposed); 8 waves (2M x 4N).
// K-tile = 64. Phases per K-tile: quad (0,0),(0,1),(1,0),(1,1).
// Stages: p0/p1 -> A halves of t+1 (other buf); p2/p3 -> B halves of t+2 (cur buf).
// vmcnt(4) once per K-tile (2 B-half stages allowed in flight).
// ---------------------------------------------------------------------------
template<int BM, int BN, bool RELU>
__global__ __launch_bounds__(512, 2)
void gemm8p(const __hip_bfloat16* __restrict__ A,
            const __hip_bfloat16* __restrict__ BT,
            const float* __restrict__ bias,
            __hip_bfloat16* __restrict__ C,
            int M, int K, int Nout)
{
    constexpr int MF = BM / 32;     // m-frags per wave
    constexpr int NF = BN / 64;     // n-frags per wave
    constexpr int MH = MF / 2;
    constexpr int NH = NF / 2;
    constexpr int LA = BM / 128;    // 64-row stage calls per A half
    constexpr int LB = BN / 128;    // per B half
    constexpr int BUFB = (BM + BN) * 128;
    __shared__ __align__(1024) char lds[2 * BUFB];

    const int tid  = threadIdx.x;
    const int wave = tid >> 6, lane = tid & 63;
    const int wm = wave >> 2, wn = wave & 3;
    const int l15 = lane & 15, lhi = lane >> 4;

    // XCD-aware swizzle (grid size is a multiple of 8)
    const int nwg = gridDim.x;
    const int bid = blockIdx.x;
    const int wg  = (bid & 7) * (nwg >> 3) + (bid >> 3);
    const int NBN = Nout / BN;
    const int bm = wg / NBN, bn = wg % NBN;

    const int NT = K >> 6;
    const __hip_bfloat16* gA = A  + (size_t)(bm * BM) * K;
    const __hip_bfloat16* gB = BT + (size_t)(bn * BN) * K;

    // prologue: B0(0), B1(0), A0(0), A1(0), B0(1), B1(1)
    {
        char* A0b = lds;
        char* B0b = lds + BM * 128;
        char* B1b = lds + BUFB + BM * 128;
        #pragma unroll
        for (int s = 0; s < LB; ++s) stage64(gB + (size_t)(s * 64) * K, K, B0b + s * 64 * 128, tid);
        #pragma unroll
        for (int s = 0; s < LB; ++s) stage64(gB + (size_t)(BN / 2 + s * 64) * K, K, B0b + (BN / 2 + s * 64) * 128, tid);
        #pragma unroll
        for (int s = 0; s < LA; ++s) stage64(gA + (size_t)(s * 64) * K, K, A0b + s * 64 * 128, tid);
        #pragma unroll
        for (int s = 0; s < LA; ++s) stage64(gA + (size_t)(BM / 2 + s * 64) * K, K, A0b + (BM / 2 + s * 64) * 128, tid);
        #pragma unroll
        for (int s = 0; s < LB; ++s) stage64(gB + (size_t)(s * 64) * K + 64, K, B1b + s * 64 * 128, tid);
        #pragma unroll
        for (int s = 0; s < LB; ++s) stage64(gB + (size_t)(BN / 2 + s * 64) * K + 64, K, B1b + (BN / 2 + s * 64) * 128, tid);
    }
    asm volatile("s_waitcnt vmcnt(4)" ::: "memory");
    __builtin_amdgcn_sched_barrier(0);
    BARRIER;

    bf16x8 af[MH][2], bf0[NH][2], bf1[NH][2];
    f32x4 acc[MF][NF] = {};

    const int arow0 = wm * (BM / 2) + l15;
    const int brow0 = wn * (BN / 4) + l15;
    const int cb = lhi * 16;

    for (int t = 0; t < NT; ++t) {
        char* Ab  = lds + (t & 1) * BUFB;
        char* Bb  = Ab + BM * 128;
        char* AbO = lds + ((t & 1) ^ 1) * BUFB;

        // -------- phase 0: read A-lo + B-lo; stage A0(t+1); MFMA quad(0,0)
        #pragma unroll
        for (int m = 0; m < MH; ++m)
            #pragma unroll
            for (int kk = 0; kk < 2; ++kk)
                af[m][kk] = ldsRead(Ab, arow0 + m * 16, kk * 64 + cb);
        #pragma unroll
        for (int n = 0; n < NH; ++n)
            #pragma unroll
            for (int kk = 0; kk < 2; ++kk)
                bf0[n][kk] = ldsRead(Bb, brow0 + n * 16, kk * 64 + cb);
        if (t + 1 < NT) {
            #pragma unroll
            for (int s = 0; s < LA; ++s)
                stage64(gA + (size_t)(s * 64) * K + (size_t)(t + 1) * 64, K, AbO + s * 64 * 128, tid);
        }
        BARRIER;
        WAIT_LGKM0;
        __builtin_amdgcn_s_setprio(1);
        #pragma unroll
        for (int m = 0; m < MH; ++m)
            #pragma unroll
            for (int n = 0; n < NH; ++n)
                #pragma unroll
                for (int kk = 0; kk < 2; ++kk)
                    acc[m][n] = __builtin_amdgcn_mfma_f32_16x16x32_bf16(af[m][kk], bf0[n][kk], acc[m][n], 0, 0, 0);
        __builtin_amdgcn_s_setprio(0);
        BARRIER;

        // -------- phase 1: read B-hi; stage A1(t+1); MFMA quad(0,1)
        #pragma unroll
        for (int n = 0; n < NH; ++n)
            #pragma unroll
            for (int kk = 0; kk < 2; ++kk)
                bf1[n][kk] = ldsRead(Bb, brow0 + (NH + n) * 16, kk * 64 + cb);
        if (t + 1 < NT) {
            #pragma unroll
            for (int s = 0; s < LA; ++s)
                stage64(gA + (size_t)(BM / 2 + s * 64) * K + (size_t)(t + 1) * 64, K, AbO + (BM / 2 + s * 64) * 128, tid);
        }
        BARRIER;
        WAIT_LGKM0;
        __builtin_amdgcn_s_setprio(1);
        #pragma unroll
        for (int m = 0; m < MH; ++m)
            #pragma unroll
            for (int n = 0; n < NH; ++n)
                #pragma unroll
                for (int kk = 0; kk < 2; ++kk)
                    acc[m][NH + n] = __builtin_amdgcn_mfma_f32_16x16x32_bf16(af[m][kk], bf1[n][kk], acc[m][NH + n], 0, 0, 0);
        __builtin_amdgcn_s_setprio(0);
        BARRIER;

        // -------- phase 2: read A-hi; stage B0(t+2); MFMA quad(1,0)
        #pragma unroll
        for (int m = 0; m < MH; ++m)
            #pragma unroll
            for (int kk = 0; kk < 2; ++kk)
                af[m][kk] = ldsRead(Ab, arow0 + (MH + m) * 16, kk * 64 + cb);
        if (t + 2 < NT) {
            #pragma unroll
            for (int s = 0; s < LB; ++s)
                stage64(gB + (size_t)(s * 64) * K + (size_t)(t + 2) * 64, K, Bb + s * 64 * 128, tid);
        }
        BARRIER;
        WAIT_LGKM0;
        __builtin_amdgcn_s_setprio(1);
        #pragma unroll
        for (int m = 0; m < MH; ++m)
            #pragma unroll
            for (int n = 0; n < NH; ++n)
                #pragma unroll
                for (int kk = 0; kk < 2; ++kk)
                    acc[MH + m][n] = __builtin_amdgcn_mfma_f32_16x16x32_bf16(af[m][kk], bf0[n][kk], acc[MH + m][n], 0, 0, 0);
        __builtin_amdgcn_s_setprio(0);
        BARRIER;

        // -------- phase 3: stage B1(t+2); MFMA quad(1,1); vmcnt; barrier
        if (t + 2 < NT) {
            #pragma unroll
            for (int s = 0; s < LB; ++s)
                stage64(gB + (size_t)(BN / 2 + s * 64) * K + (size_t)(t + 2) * 64, K, Bb + (BN / 2 + s * 64) * 128, tid);
        }
        BARRIER;
        __builtin_amdgcn_s_setprio(1);
        #pragma unroll
        for (int m = 0; m < MH; ++m)
            #pragma unroll
            for (int n = 0; n < NH; ++n)
                #pragma unroll
                for (int kk = 0; kk < 2; ++kk)
                    acc[MH + m][NH + n] = __builtin_amdgcn_mfma_f32_16x16x32_bf16(af[m][kk], bf1[n][kk], acc[MH + m][NH + n], 0, 0, 0);
        __builtin_amdgcn_s_setprio(0);
        if (t + 2 < NT) {
            asm volatile("s_waitcnt vmcnt(4)" ::: "memory");
        } else if (t + 1 < NT) {
            asm volatile("s_waitcnt vmcnt(0)" ::: "memory");
        }
        __builtin_amdgcn_sched_barrier(0);
        BARRIER;
    }

    // -------- C write: col = lane&15 (+n*16), row = lhi*4 + r (+m*16)
    const int crow0 = bm * BM + wm * (BM / 2) + lhi * 4;
    const int ccol0 = bn * BN + wn * (BN / 4) + l15;
    #pragma unroll
    for (int m = 0; m < MF; ++m) {
        #pragma unroll
        for (int n = 0; n < NF; ++n) {
            int col = ccol0 + n * 16;
            float bv = bias[col];
            #pragma unroll
            for (int r = 0; r < 4; ++r) {
                int row = crow0 + m * 16 + r;
                float v = acc[m][n][r] + bv;
                if (RELU) v = (v > 0.0f) ? v : 0.2f * v;
                C[(size_t)row * Nout + col] = __float2bfloat16(v);
            }
        }
    }
}

// ---------------------------------------------------------------------------
// Epilogue: s/t split, y assembly, per-row log_det
// ---------------------------------------------------------------------------
__global__ __launch_bounds__(256)
void epilogue_kernel(const float* __restrict__ x,
                     const __hip_bfloat16* __restrict__ outb,
                     float* __restrict__ y, float* __restrict__ ld)
{
    const int i = blockIdx.x;
    const int t = threadIdx.x;
    const __hip_bfloat16* orow = outb + (size_t)i * LFULL;
    const float* xrow = x + (size_t)i * LFULL;
    float* yrow = y + (size_t)i * LFULL;

    const int j0 = t * 8;
    u16x8 sv = *(const u16x8*)(orow + j0);
    u16x8 tv = *(const u16x8*)(orow + NHALF + j0);

    float part = 0.0f;
    #pragma unroll
    for (int u = 0; u < 8; u += 2) {
        float4 xv = *(const float4*)(xrow + 2 * (j0 + u));
        float s0 = bf2f(sv[u]),     s1 = bf2f(sv[u + 1]);
        float t0 = bf2f(tv[u]),     t1 = bf2f(tv[u + 1]);
        float a0 = 2.0f * fast_tanh(s0);
        float a1 = 2.0f * fast_tanh(s1);
        part += a0 + a1;
        float4 yv;
        yv.x = xv.x;  yv.y = xv.y * __expf(a0) + t0;
        yv.z = xv.z;  yv.w = xv.w * __expf(a1) + t1;
        *(float4*)(yrow + 2 * (j0 + u)) = yv;
    }

    #pragma unroll
    for (int off = 32; off; off >>= 1) part += __shfl_down(part, off, 64);
    __shared__ float red[4];
    if ((t & 63) == 0) red[t >> 6] = part;
    __syncthreads();
    if (t == 0) ld[i] = red[0] + red[1] + red[2] + red[3];
}

// ---------------------------------------------------------------------------
extern "C" void kernel_launch(void* const* d_in, const int* in_sizes, int n_in,
                              void* d_out, int out_size, void* d_ws, size_t ws_size,
                              hipStream_t stream)
{
    const float* x  = (const float*)d_in[0];
    const float* W1 = (const float*)d_in[1];
    const float* b1 = (const float*)d_in[2];
    const float* W2 = (const float*)d_in[3];
    const float* b2 = (const float*)d_in[4];
    const float* W3 = (const float*)d_in[5];
    const float* b3 = (const float*)d_in[6];

    char* ws = (char*)d_ws;
    const size_t MB = 1u << 20;
    __hip_bfloat16* W3T  = (__hip_bfloat16*)(ws);              // 16 MB: 4096x2048
    __hip_bfloat16* h2   = (__hip_bfloat16*)(ws + 16 * MB);    // 16 MB: 4096x2048
    __hip_bfloat16* xmb  = (__hip_bfloat16*)(ws + 32 * MB);    // 16 MB
    __hip_bfloat16* W1T  = (__hip_bfloat16*)(ws + 48 * MB);    //  8 MB
    __hip_bfloat16* W2T  = (__hip_bfloat16*)(ws + 56 * MB);    //  8 MB
    __hip_bfloat16* h1   = (__hip_bfloat16*)(ws + 64 * MB);    // 16 MB
    __hip_bfloat16* outb = (__hip_bfloat16*)(ws + 32 * MB);    // 32 MB (overlays xmb/W1T/W2T)

    float* y  = (float*)d_out;
    float* ld = y + (size_t)MROWS * LFULL;

    cast_x_kernel<<<4096, 256, 0, stream>>>(x, xmb);
    transpose_cast_kernel<<<dim3(32, 32), 256, 0, stream>>>(W1, W1T, HDIM, HDIM);
    transpose_cast_kernel<<<dim3(32, 32), 256, 0, stream>>>(W2, W2T, HDIM, HDIM);
    transpose_cast_kernel<<<dim3(64, 32), 256, 0, stream>>>(W3, W3T, HDIM, LFULL);

    gemm8p<128, 256, true ><<<dim3(256), dim3(512), 0, stream>>>(xmb, W1T, b1, h1, MROWS, HDIM, HDIM);
    gemm8p<128, 256, true ><<<dim3(256), dim3(512), 0, stream>>>(h1,  W2T, b2, h2, MROWS, HDIM, HDIM);
    gemm8p<256, 256, false><<<dim3(256), dim3(512), 0, stream>>>(h2,  W3T, b3, outb, MROWS, HDIM, LFULL);

    epilogue_kernel<<<4096, 256, 0, stream>>>(x, outb, y, ld);
}

// Round 3
// 218.881 us; speedup vs baseline: 1.1838x; 1.0518x over previous
//
#include <hip/hip_runtime.h>
#include <hip/hip_bf16.h>
#include <stdint.h>

// Problem sizes (fixed)
#define MROWS 4096   // batch B
#define LFULL 4096   // L
#define NHALF 2048   // N = L/2
#define HDIM  2048   // H

typedef __bf16 bf16x8 __attribute__((ext_vector_type(8)));
typedef float  f32x4  __attribute__((ext_vector_type(4)));
typedef unsigned short u16x8 __attribute__((ext_vector_type(8)));

__device__ __forceinline__ unsigned short f2bf(float f) {
    __hip_bfloat16 h = __float2bfloat16(f);
    return __builtin_bit_cast(unsigned short, h);
}
__device__ __forceinline__ float bf2f(unsigned short u) {
    return __builtin_bit_cast(float, (uint32_t)u << 16);
}
__device__ __forceinline__ float fast_tanh(float x) {
    float ax = fabsf(x);
    float e  = __expf(-2.0f * ax);
    float t  = (1.0f - e) / (1.0f + e);
    return copysignf(t, x);
}

__device__ __forceinline__ void gload_lds16(const void* g, void* l) {
    __builtin_amdgcn_global_load_lds(
        (const __attribute__((address_space(1))) uint32_t*)g,
        (__attribute__((address_space(3))) uint32_t*)l,
        16, 0, 0);
}

#define WAIT_LGKM0 do { asm volatile("s_waitcnt lgkmcnt(0)" ::: "memory"); __builtin_amdgcn_sched_barrier(0); } while (0)
#define BARRIER    do { __builtin_amdgcn_s_barrier(); __builtin_amdgcn_sched_barrier(0); } while (0)

// Stage one 64-row x 64-col bf16 segment: 512 threads x 16B, linear LDS dest,
// XOR-swizzled global source chunk: chunk c reads global chunk c^(row&7) so a
// later swizzled ds_read (byte ^= (row&7)<<4) sees the natural layout.
__device__ __forceinline__ void stage64(const __hip_bfloat16* g, int ldK, char* ldsHalf, int tid) {
    int r = tid >> 3, c = tid & 7;
    int sc = c ^ (r & 7);                        // full 3-bit bank-quad swizzle
    gload_lds16(g + (size_t)r * ldK + sc * 8, ldsHalf + r * 128 + c * 16);
}

// Swizzled ds_read of a 16B MFMA fragment slice. row in tile, colByte in [0,128)
__device__ __forceinline__ bf16x8 ldsRead(const char* tileBase, int row, int colByte) {
    int off = row * 128 + (colByte ^ ((row & 7) << 4));   // spread 16 rows over 8 bank-quads
    return *(const bf16x8*)(tileBase + off);
}

// ---------------------------------------------------------------------------
// Cast x even columns -> bf16 x_m (MROWS x NHALF)
// ---------------------------------------------------------------------------
__global__ __launch_bounds__(256)
void cast_x_kernel(const float* __restrict__ x, __hip_bfloat16* __restrict__ xm)
{
    size_t t = (size_t)blockIdx.x * 256 + threadIdx.x;
    size_t r = t >> 8;
    int    c = (int)(t & 255);
    const float4* xp = (const float4*)(x + r * LFULL + (size_t)c * 16);
    float4 a = xp[0], b = xp[1], d = xp[2], e = xp[3];
    u16x8 v;
    v[0] = f2bf(a.x); v[1] = f2bf(a.z);
    v[2] = f2bf(b.x); v[3] = f2bf(b.z);
    v[4] = f2bf(d.x); v[5] = f2bf(d.z);
    v[6] = f2bf(e.x); v[7] = f2bf(e.z);
    *(u16x8*)(xm + r * NHALF + (size_t)c * 8) = v;
}

// ---------------------------------------------------------------------------
// Transpose + cast: W (K x N, f32) -> WT (N x K, bf16)
// ---------------------------------------------------------------------------
__global__ __launch_bounds__(256)
void transpose_cast_kernel(const float* __restrict__ W, __hip_bfloat16* __restrict__ WT,
                           int K, int N)
{
    __shared__ unsigned short lds[64][66];
    const int t  = threadIdx.x;
    const int k0 = blockIdx.y * 64;
    const int n0 = blockIdx.x * 64;

    #pragma unroll
    for (int it = 0; it < 4; ++it) {
        int kl = it * 16 + (t >> 4);
        int nl = (t & 15) * 4;
        float4 v = *(const float4*)(W + (size_t)(k0 + kl) * N + n0 + nl);
        lds[kl][nl + 0] = f2bf(v.x);
        lds[kl][nl + 1] = f2bf(v.y);
        lds[kl][nl + 2] = f2bf(v.z);
        lds[kl][nl + 3] = f2bf(v.w);
    }
    __syncthreads();

    int nl = t >> 2;
    int kc = (t & 3) * 16;
    unsigned short tmp[16];
    #pragma unroll
    for (int j = 0; j < 16; ++j) tmp[j] = lds[kc + j][nl];
    u16x8* dst = (u16x8*)(WT + (size_t)(n0 + nl) * K + k0 + kc);
    dst[0] = *(u16x8*)&tmp[0];
    dst[1] = *(u16x8*)&tmp[8];
}

// ---------------------------------------------------------------------------
// 8-phase 256-class GEMM: C = act(A @ B + bias)
// A: MxK bf16 row-major; BT: Nout x K bf16 (B transposed); 8 waves (2M x 4N).
// K-tile = 64. Phases per K-tile: quad (0,0),(0,1),(1,0),(1,1).
// Stages: p0/p1 -> A halves of t+1 (other buf); p2/p3 -> B halves of t+2 (cur buf).
// vmcnt(4) once per K-tile (B halves of t+2 allowed in flight).
// ---------------------------------------------------------------------------
template<int BM, int BN, bool RELU>
__global__ __launch_bounds__(512, 2)
void gemm8p(const __hip_bfloat16* __restrict__ A,
            const __hip_bfloat16* __restrict__ BT,
            const float* __restrict__ bias,
            __hip_bfloat16* __restrict__ C,
            int M, int K, int Nout)
{
    constexpr int MF = BM / 32;     // m-frags per wave
    constexpr int NF = BN / 64;     // n-frags per wave
    constexpr int MH = MF / 2;
    constexpr int NH = NF / 2;
    constexpr int LA = BM / 128;    // 64-row stage calls per A half
    constexpr int LB = BN / 128;    // per B half
    constexpr int BUFB = (BM + BN) * 128;
    __shared__ __align__(1024) char lds[2 * BUFB];

    const int tid  = threadIdx.x;
    const int wave = tid >> 6, lane = tid & 63;
    const int wm = wave >> 2, wn = wave & 3;
    const int l15 = lane & 15, lhi = lane >> 4;

    // XCD-aware swizzle (grid size is a multiple of 8)
    const int nwg = gridDim.x;
    const int bid = blockIdx.x;
    const int wg  = (bid & 7) * (nwg >> 3) + (bid >> 3);
    const int NBN = Nout / BN;
    const int bm = wg / NBN, bn = wg % NBN;

    const int NT = K >> 6;
    const __hip_bfloat16* gA = A  + (size_t)(bm * BM) * K;
    const __hip_bfloat16* gB = BT + (size_t)(bn * BN) * K;

    // prologue: B0(0), B1(0), A0(0), A1(0), B0(1), B1(1)
    {
        char* A0b = lds;
        char* B0b = lds + BM * 128;
        char* B1b = lds + BUFB + BM * 128;
        #pragma unroll
        for (int s = 0; s < LB; ++s) stage64(gB + (size_t)(s * 64) * K, K, B0b + s * 64 * 128, tid);
        #pragma unroll
        for (int s = 0; s < LB; ++s) stage64(gB + (size_t)(BN / 2 + s * 64) * K, K, B0b + (BN / 2 + s * 64) * 128, tid);
        #pragma unroll
        for (int s = 0; s < LA; ++s) stage64(gA + (size_t)(s * 64) * K, K, A0b + s * 64 * 128, tid);
        #pragma unroll
        for (int s = 0; s < LA; ++s) stage64(gA + (size_t)(BM / 2 + s * 64) * K, K, A0b + (BM / 2 + s * 64) * 128, tid);
        #pragma unroll
        for (int s = 0; s < LB; ++s) stage64(gB + (size_t)(s * 64) * K + 64, K, B1b + s * 64 * 128, tid);
        #pragma unroll
        for (int s = 0; s < LB; ++s) stage64(gB + (size_t)(BN / 2 + s * 64) * K + 64, K, B1b + (BN / 2 + s * 64) * 128, tid);
    }
    asm volatile("s_waitcnt vmcnt(4)" ::: "memory");
    __builtin_amdgcn_sched_barrier(0);
    BARRIER;

    bf16x8 af[MH][2], bf0[NH][2], bf1[NH][2];
    f32x4 acc[MF][NF] = {};

    const int arow0 = wm * (BM / 2) + l15;
    const int brow0 = wn * (BN / 4) + l15;
    const int cb = lhi * 16;

    for (int t = 0; t < NT; ++t) {
        char* Ab  = lds + (t & 1) * BUFB;
        char* Bb  = Ab + BM * 128;
        char* AbO = lds + ((t & 1) ^ 1) * BUFB;

        // -------- phase 0: read A-lo + B-lo; stage A0(t+1); MFMA quad(0,0)
        #pragma unroll
        for (int m = 0; m < MH; ++m)
            #pragma unroll
            for (int kk = 0; kk < 2; ++kk)
                af[m][kk] = ldsRead(Ab, arow0 + m * 16, kk * 64 + cb);
        #pragma unroll
        for (int n = 0; n < NH; ++n)
            #pragma unroll
            for (int kk = 0; kk < 2; ++kk)
                bf0[n][kk] = ldsRead(Bb, brow0 + n * 16, kk * 64 + cb);
        if (t + 1 < NT) {
            #pragma unroll
            for (int s = 0; s < LA; ++s)
                stage64(gA + (size_t)(s * 64) * K + (size_t)(t + 1) * 64, K, AbO + s * 64 * 128, tid);
        }
        BARRIER;
        WAIT_LGKM0;
        __builtin_amdgcn_s_setprio(1);
        #pragma unroll
        for (int m = 0; m < MH; ++m)
            #pragma unroll
            for (int n = 0; n < NH; ++n)
                #pragma unroll
                for (int kk = 0; kk < 2; ++kk)
                    acc[m][n] = __builtin_amdgcn_mfma_f32_16x16x32_bf16(af[m][kk], bf0[n][kk], acc[m][n], 0, 0, 0);
        __builtin_amdgcn_s_setprio(0);
        BARRIER;

        // -------- phase 1: read B-hi; stage A1(t+1); MFMA quad(0,1)
        #pragma unroll
        for (int n = 0; n < NH; ++n)
            #pragma unroll
            for (int kk = 0; kk < 2; ++kk)
                bf1[n][kk] = ldsRead(Bb, brow0 + (NH + n) * 16, kk * 64 + cb);
        if (t + 1 < NT) {
            #pragma unroll
            for (int s = 0; s < LA; ++s)
                stage64(gA + (size_t)(BM / 2 + s * 64) * K + (size_t)(t + 1) * 64, K, AbO + (BM / 2 + s * 64) * 128, tid);
        }
        BARRIER;
        WAIT_LGKM0;
        __builtin_amdgcn_s_setprio(1);
        #pragma unroll
        for (int m = 0; m < MH; ++m)
            #pragma unroll
            for (int n = 0; n < NH; ++n)
                #pragma unroll
                for (int kk = 0; kk < 2; ++kk)
                    acc[m][NH + n] = __builtin_amdgcn_mfma_f32_16x16x32_bf16(af[m][kk], bf1[n][kk], acc[m][NH + n], 0, 0, 0);
        __builtin_amdgcn_s_setprio(0);
        BARRIER;

        // -------- phase 2: read A-hi; stage B0(t+2); MFMA quad(1,0)
        #pragma unroll
        for (int m = 0; m < MH; ++m)
            #pragma unroll
            for (int kk = 0; kk < 2; ++kk)
                af[m][kk] = ldsRead(Ab, arow0 + (MH + m) * 16, kk * 64 + cb);
        if (t + 2 < NT) {
            #pragma unroll
            for (int s = 0; s < LB; ++s)
                stage64(gB + (size_t)(s * 64) * K + (size_t)(t + 2) * 64, K, Bb + s * 64 * 128, tid);
        }
        BARRIER;
        WAIT_LGKM0;
        __builtin_amdgcn_s_setprio(1);
        #pragma unroll
        for (int m = 0; m < MH; ++m)
            #pragma unroll
            for (int n = 0; n < NH; ++n)
                #pragma unroll
                for (int kk = 0; kk < 2; ++kk)
                    acc[MH + m][n] = __builtin_amdgcn_mfma_f32_16x16x32_bf16(af[m][kk], bf0[n][kk], acc[MH + m][n], 0, 0, 0);
        __builtin_amdgcn_s_setprio(0);
        BARRIER;

        // -------- phase 3: stage B1(t+2); MFMA quad(1,1); vmcnt; barrier
        if (t + 2 < NT) {
            #pragma unroll
            for (int s = 0; s < LB; ++s)
                stage64(gB + (size_t)(BN / 2 + s * 64) * K + (size_t)(t + 2) * 64, K, Bb + (BN / 2 + s * 64) * 128, tid);
        }
        BARRIER;
        __builtin_amdgcn_s_setprio(1);
        #pragma unroll
        for (int m = 0; m < MH; ++m)
            #pragma unroll
            for (int n = 0; n < NH; ++n)
                #pragma unroll
                for (int kk = 0; kk < 2; ++kk)
                    acc[MH + m][NH + n] = __builtin_amdgcn_mfma_f32_16x16x32_bf16(af[m][kk], bf1[n][kk], acc[MH + m][NH + n], 0, 0, 0);
        __builtin_amdgcn_s_setprio(0);
        if (t + 2 < NT) {
            asm volatile("s_waitcnt vmcnt(4)" ::: "memory");
        } else if (t + 1 < NT) {
            asm volatile("s_waitcnt vmcnt(0)" ::: "memory");
        }
        __builtin_amdgcn_sched_barrier(0);
        BARRIER;
    }

    // -------- C write: col = lane&15 (+n*16), row = lhi*4 + r (+m*16)
    const int crow0 = bm * BM + wm * (BM / 2) + lhi * 4;
    const int ccol0 = bn * BN + wn * (BN / 4) + l15;
    #pragma unroll
    for (int m = 0; m < MF; ++m) {
        #pragma unroll
        for (int n = 0; n < NF; ++n) {
            int col = ccol0 + n * 16;
            float bv = bias[col];
            #pragma unroll
            for (int r = 0; r < 4; ++r) {
                int row = crow0 + m * 16 + r;
                float v = acc[m][n][r] + bv;
                if (RELU) v = (v > 0.0f) ? v : 0.2f * v;
                C[(size_t)row * Nout + col] = __float2bfloat16(v);
            }
        }
    }
}

// ---------------------------------------------------------------------------
// Epilogue: s/t split, y assembly, per-row log_det
// ---------------------------------------------------------------------------
__global__ __launch_bounds__(256)
void epilogue_kernel(const float* __restrict__ x,
                     const __hip_bfloat16* __restrict__ outb,
                     float* __restrict__ y, float* __restrict__ ld)
{
    const int i = blockIdx.x;
    const int t = threadIdx.x;
    const __hip_bfloat16* orow = outb + (size_t)i * LFULL;
    const float* xrow = x + (size_t)i * LFULL;
    float* yrow = y + (size_t)i * LFULL;

    const int j0 = t * 8;
    u16x8 sv = *(const u16x8*)(orow + j0);
    u16x8 tv = *(const u16x8*)(orow + NHALF + j0);

    float part = 0.0f;
    #pragma unroll
    for (int u = 0; u < 8; u += 2) {
        float4 xv = *(const float4*)(xrow + 2 * (j0 + u));
        float s0 = bf2f(sv[u]),     s1 = bf2f(sv[u + 1]);
        float t0 = bf2f(tv[u]),     t1 = bf2f(tv[u + 1]);
        float a0 = 2.0f * fast_tanh(s0);
        float a1 = 2.0f * fast_tanh(s1);
        part += a0 + a1;
        float4 yv;
        yv.x = xv.x;  yv.y = xv.y * __expf(a0) + t0;
        yv.z = xv.z;  yv.w = xv.w * __expf(a1) + t1;
        *(float4*)(yrow + 2 * (j0 + u)) = yv;
    }

    #pragma unroll
    for (int off = 32; off; off >>= 1) part += __shfl_down(part, off, 64);
    __shared__ float red[4];
    if ((t & 63) == 0) red[t >> 6] = part;
    __syncthreads();
    if (t == 0) ld[i] = red[0] + red[1] + red[2] + red[3];
}

// ---------------------------------------------------------------------------
extern "C" void kernel_launch(void* const* d_in, const int* in_sizes, int n_in,
                              void* d_out, int out_size, void* d_ws, size_t ws_size,
                              hipStream_t stream)
{
    const float* x  = (const float*)d_in[0];
    const float* W1 = (const float*)d_in[1];
    const float* b1 = (const float*)d_in[2];
    const float* W2 = (const float*)d_in[3];
    const float* b2 = (const float*)d_in[4];
    const float* W3 = (const float*)d_in[5];
    const float* b3 = (const float*)d_in[6];

    char* ws = (char*)d_ws;
    const size_t MB = 1u << 20;
    __hip_bfloat16* W3T  = (__hip_bfloat16*)(ws);              // 16 MB: 4096x2048
    __hip_bfloat16* h2   = (__hip_bfloat16*)(ws + 16 * MB);    // 16 MB: 4096x2048
    __hip_bfloat16* xmb  = (__hip_bfloat16*)(ws + 32 * MB);    // 16 MB
    __hip_bfloat16* W1T  = (__hip_bfloat16*)(ws + 48 * MB);    //  8 MB
    __hip_bfloat16* W2T  = (__hip_bfloat16*)(ws + 56 * MB);    //  8 MB
    __hip_bfloat16* h1   = (__hip_bfloat16*)(ws + 64 * MB);    // 16 MB
    __hip_bfloat16* outb = (__hip_bfloat16*)(ws + 32 * MB);    // 32 MB (overlays xmb/W1T/W2T)

    float* y  = (float*)d_out;
    float* ld = y + (size_t)MROWS * LFULL;

    cast_x_kernel<<<4096, 256, 0, stream>>>(x, xmb);
    transpose_cast_kernel<<<dim3(32, 32), 256, 0, stream>>>(W1, W1T, HDIM, HDIM);
    transpose_cast_kernel<<<dim3(32, 32), 256, 0, stream>>>(W2, W2T, HDIM, HDIM);
    transpose_cast_kernel<<<dim3(64, 32), 256, 0, stream>>>(W3, W3T, HDIM, LFULL);

    gemm8p<128, 256, true ><<<dim3(256), dim3(512), 0, stream>>>(xmb, W1T, b1, h1, MROWS, HDIM, HDIM);
    gemm8p<128, 256, true ><<<dim3(256), dim3(512), 0, stream>>>(h1,  W2T, b2, h2, MROWS, HDIM, HDIM);
    gemm8p<256, 256, false><<<dim3(256), dim3(512), 0, stream>>>(h2,  W3T, b3, outb, MROWS, HDIM, LFULL);

    epilogue_kernel<<<4096, 256, 0, stream>>>(x, outb, y, ld);
}

// Round 4
// 218.655 us; speedup vs baseline: 1.1850x; 1.0010x over previous
//
#include <hip/hip_runtime.h>
#include <hip/hip_bf16.h>
#include <stdint.h>

// Problem sizes (fixed)
#define MROWS 4096   // batch B
#define LFULL 4096   // L
#define NHALF 2048   // N = L/2
#define HDIM  2048   // H

typedef __bf16 bf16x8 __attribute__((ext_vector_type(8)));
typedef float  f32x4  __attribute__((ext_vector_type(4)));
typedef unsigned short u16x8 __attribute__((ext_vector_type(8)));

__device__ __forceinline__ unsigned short f2bf(float f) {
    __hip_bfloat16 h = __float2bfloat16(f);
    return __builtin_bit_cast(unsigned short, h);
}
__device__ __forceinline__ float bf2f(unsigned short u) {
    return __builtin_bit_cast(float, (uint32_t)u << 16);
}
__device__ __forceinline__ float fast_tanh(float x) {
    float ax = fabsf(x);
    float e  = __expf(-2.0f * ax);
    float t  = (1.0f - e) / (1.0f + e);
    return copysignf(t, x);
}

__device__ __forceinline__ void gload_lds16(const void* g, void* l) {
    __builtin_amdgcn_global_load_lds(
        (const __attribute__((address_space(1))) uint32_t*)g,
        (__attribute__((address_space(3))) uint32_t*)l,
        16, 0, 0);
}

#define SBAR    __builtin_amdgcn_sched_barrier(0)
#define BARRIER do { __builtin_amdgcn_s_barrier(); SBAR; } while (0)

// Stage one 64-row x 64-col bf16 segment: 512 threads x 16B, linear LDS dest,
// XOR-swizzled global source chunk (chunk c <- c^(row&7)); paired with the
// swizzled ds_read below (byte ^= (row&7)<<4).
__device__ __forceinline__ void stage64(const __hip_bfloat16* g, int ldK, char* ldsHalf, int tid) {
    int r = tid >> 3, c = tid & 7;
    int sc = c ^ (r & 7);
    gload_lds16(g + (size_t)r * ldK + sc * 8, ldsHalf + r * 128 + c * 16);
}

__device__ __forceinline__ bf16x8 ldsRead(const char* tileBase, int row, int colByte) {
    int off = row * 128 + (colByte ^ ((row & 7) << 4));
    return *(const bf16x8*)(tileBase + off);
}

// ---------------------------------------------------------------------------
// Cast x even columns -> bf16 x_m (MROWS x NHALF)
// ---------------------------------------------------------------------------
__global__ __launch_bounds__(256)
void cast_x_kernel(const float* __restrict__ x, __hip_bfloat16* __restrict__ xm)
{
    size_t t = (size_t)blockIdx.x * 256 + threadIdx.x;
    size_t r = t >> 8;
    int    c = (int)(t & 255);
    const float4* xp = (const float4*)(x + r * LFULL + (size_t)c * 16);
    float4 a = xp[0], b = xp[1], d = xp[2], e = xp[3];
    u16x8 v;
    v[0] = f2bf(a.x); v[1] = f2bf(a.z);
    v[2] = f2bf(b.x); v[3] = f2bf(b.z);
    v[4] = f2bf(d.x); v[5] = f2bf(d.z);
    v[6] = f2bf(e.x); v[7] = f2bf(e.z);
    *(u16x8*)(xm + r * NHALF + (size_t)c * 8) = v;
}

// ---------------------------------------------------------------------------
// Transpose + cast: W (K x N, f32) -> WT (N x K, bf16)
// ---------------------------------------------------------------------------
__global__ __launch_bounds__(256)
void transpose_cast_kernel(const float* __restrict__ W, __hip_bfloat16* __restrict__ WT,
                           int K, int N)
{
    __shared__ unsigned short lds[64][66];
    const int t  = threadIdx.x;
    const int k0 = blockIdx.y * 64;
    const int n0 = blockIdx.x * 64;

    #pragma unroll
    for (int it = 0; it < 4; ++it) {
        int kl = it * 16 + (t >> 4);
        int nl = (t & 15) * 4;
        float4 v = *(const float4*)(W + (size_t)(k0 + kl) * N + n0 + nl);
        lds[kl][nl + 0] = f2bf(v.x);
        lds[kl][nl + 1] = f2bf(v.y);
        lds[kl][nl + 2] = f2bf(v.z);
        lds[kl][nl + 3] = f2bf(v.w);
    }
    __syncthreads();

    int nl = t >> 2;
    int kc = (t & 3) * 16;
    unsigned short tmp[16];
    #pragma unroll
    for (int j = 0; j < 16; ++j) tmp[j] = lds[kc + j][nl];
    u16x8* dst = (u16x8*)(WT + (size_t)(n0 + nl) * K + k0 + kc);
    dst[0] = *(u16x8*)&tmp[0];
    dst[1] = *(u16x8*)&tmp[8];
}

// ---------------------------------------------------------------------------
// 8-phase GEMM with one-phase-ahead fragment pipelining.
// A: MxK bf16 row-major; BT: Nout x K bf16; 8 waves (2M x 4N); K-tile = 64.
// Quads: p0=(0,0) p1=(0,1) p2=(1,0) p3=(1,1).
// Reads (all >=1 phase ahead of use, same reg arrays, clean lifetime handoff):
//   bHI(t)  @ p0-top        (used p1, p3)
//   aHI(t)  @ p1-post-MFMA  (used p2, p3)   [af: aLO dead after p1 MFMA]
//   bLO(t+1)@ p3 post-vmcnt (used p0')      [bf0: bLO dead after p2]
//   aLO(t+1)@ p3-post-MFMA  (used p0', p1') [af: aHI dead after p3 MFMA]
// Stages: p0/p1 -> A halves(t+1) other buf; p2/p3 -> B halves(t+2) cur buf.
// vmcnt(4) at p3 guarantees A(t+1) and B(t+1) landed before the t+1 reads.
// ---------------------------------------------------------------------------
template<int BM, int BN, bool RELU>
__global__ __launch_bounds__(512, 2)
void gemm8p(const __hip_bfloat16* __restrict__ A,
            const __hip_bfloat16* __restrict__ BT,
            const float* __restrict__ bias,
            __hip_bfloat16* __restrict__ C,
            int M, int K, int Nout)
{
    constexpr int MF = BM / 32;
    constexpr int NF = BN / 64;
    constexpr int MH = MF / 2;
    constexpr int NH = NF / 2;
    constexpr int LA = BM / 128;
    constexpr int LB = BN / 128;
    constexpr int BUFB = (BM + BN) * 128;
    __shared__ __align__(1024) char lds[2 * BUFB];

    const int tid  = threadIdx.x;
    const int wave = tid >> 6, lane = tid & 63;
    const int wm = wave >> 2, wn = wave & 3;
    const int l15 = lane & 15, lhi = lane >> 4;

    const int nwg = gridDim.x;
    const int bid = blockIdx.x;
    const int wg  = (bid & 7) * (nwg >> 3) + (bid >> 3);
    const int NBN = Nout / BN;
    const int bm = wg / NBN, bn = wg % NBN;

    const int NT = K >> 6;
    const __hip_bfloat16* gA = A  + (size_t)(bm * BM) * K;
    const __hip_bfloat16* gB = BT + (size_t)(bn * BN) * K;

    // prologue: B0(0), B1(0), A0(0), A1(0), B0(1), B1(1)
    {
        char* A0b = lds;
        char* B0b = lds + BM * 128;
        char* B1b = lds + BUFB + BM * 128;
        #pragma unroll
        for (int s = 0; s < LB; ++s) stage64(gB + (size_t)(s * 64) * K, K, B0b + s * 64 * 128, tid);
        #pragma unroll
        for (int s = 0; s < LB; ++s) stage64(gB + (size_t)(BN / 2 + s * 64) * K, K, B0b + (BN / 2 + s * 64) * 128, tid);
        #pragma unroll
        for (int s = 0; s < LA; ++s) stage64(gA + (size_t)(s * 64) * K, K, A0b + s * 64 * 128, tid);
        #pragma unroll
        for (int s = 0; s < LA; ++s) stage64(gA + (size_t)(BM / 2 + s * 64) * K, K, A0b + (BM / 2 + s * 64) * 128, tid);
        #pragma unroll
        for (int s = 0; s < LB; ++s) stage64(gB + (size_t)(s * 64) * K + 64, K, B1b + s * 64 * 128, tid);
        #pragma unroll
        for (int s = 0; s < LB; ++s) stage64(gB + (size_t)(BN / 2 + s * 64) * K + 64, K, B1b + (BN / 2 + s * 64) * 128, tid);
    }
    asm volatile("s_waitcnt vmcnt(4)" ::: "memory");
    SBAR;
    BARRIER;

    bf16x8 af[MH][2], bf0[NH][2], bf1[NH][2];
    f32x4 acc[MF][NF] = {};

    const int arow0 = wm * (BM / 2) + l15;
    const int brow0 = wn * (BN / 4) + l15;
    const int cb = lhi * 16;

    // pre-read aLO(0), bLO(0)
    #pragma unroll
    for (int m = 0; m < MH; ++m)
        #pragma unroll
        for (int kk = 0; kk < 2; ++kk)
            af[m][kk] = ldsRead(lds, arow0 + m * 16, kk * 64 + cb);
    #pragma unroll
    for (int n = 0; n < NH; ++n)
        #pragma unroll
        for (int kk = 0; kk < 2; ++kk)
            bf0[n][kk] = ldsRead(lds + BM * 128, brow0 + n * 16, kk * 64 + cb);
    SBAR;

    for (int t = 0; t < NT; ++t) {
        char* Ab  = lds + (t & 1) * BUFB;
        char* Bb  = Ab + BM * 128;
        char* AbO = lds + ((t & 1) ^ 1) * BUFB;
        char* BbO = AbO + BM * 128;

        // ---- phase 0: read bHI(t); stage A0(t+1); MFMA q(0,0)=aLO*bLO
        #pragma unroll
        for (int n = 0; n < NH; ++n)
            #pragma unroll
            for (int kk = 0; kk < 2; ++kk)
                bf1[n][kk] = ldsRead(Bb, brow0 + (NH + n) * 16, kk * 64 + cb);
        if (t + 1 < NT) {
            #pragma unroll
            for (int s = 0; s < LA; ++s)
                stage64(gA + (size_t)(s * 64) * K + (size_t)(t + 1) * 64, K, AbO + s * 64 * 128, tid);
        }
        BARRIER;
        __builtin_amdgcn_s_setprio(1);
        #pragma unroll
        for (int m = 0; m < MH; ++m)
            #pragma unroll
            for (int n = 0; n < NH; ++n)
                #pragma unroll
                for (int kk = 0; kk < 2; ++kk)
                    acc[m][n] = __builtin_amdgcn_mfma_f32_16x16x32_bf16(af[m][kk], bf0[n][kk], acc[m][n], 0, 0, 0);
        __builtin_amdgcn_s_setprio(0);
        BARRIER;

        // ---- phase 1: stage A1(t+1); MFMA q(0,1)=aLO*bHI; then read aHI(t)
        if (t + 1 < NT) {
            #pragma unroll
            for (int s = 0; s < LA; ++s)
                stage64(gA + (size_t)(BM / 2 + s * 64) * K + (size_t)(t + 1) * 64, K, AbO + (BM / 2 + s * 64) * 128, tid);
        }
        BARRIER;
        __builtin_amdgcn_s_setprio(1);
        #pragma unroll
        for (int m = 0; m < MH; ++m)
            #pragma unroll
            for (int n = 0; n < NH; ++n)
                #pragma unroll
                for (int kk = 0; kk < 2; ++kk)
                    acc[m][NH + n] = __builtin_amdgcn_mfma_f32_16x16x32_bf16(af[m][kk], bf1[n][kk], acc[m][NH + n], 0, 0, 0);
        __builtin_amdgcn_s_setprio(0);
        SBAR;
        #pragma unroll
        for (int m = 0; m < MH; ++m)
            #pragma unroll
            for (int kk = 0; kk < 2; ++kk)
                af[m][kk] = ldsRead(Ab, arow0 + (MH + m) * 16, kk * 64 + cb);
        BARRIER;

        // ---- phase 2: stage B0(t+2); MFMA q(1,0)=aHI*bLO
        if (t + 2 < NT) {
            #pragma unroll
            for (int s = 0; s < LB; ++s)
                stage64(gB + (size_t)(s * 64) * K + (size_t)(t + 2) * 64, K, Bb + s * 64 * 128, tid);
        }
        BARRIER;
        __builtin_amdgcn_s_setprio(1);
        #pragma unroll
        for (int m = 0; m < MH; ++m)
            #pragma unroll
            for (int n = 0; n < NH; ++n)
                #pragma unroll
                for (int kk = 0; kk < 2; ++kk)
                    acc[MH + m][n] = __builtin_amdgcn_mfma_f32_16x16x32_bf16(af[m][kk], bf0[n][kk], acc[MH + m][n], 0, 0, 0);
        __builtin_amdgcn_s_setprio(0);
        BARRIER;

        // ---- phase 3: stage B1(t+2); vmcnt; read bLO(t+1); MFMA q(1,1)=aHI*bHI; read aLO(t+1)
        if (t + 2 < NT) {
            #pragma unroll
            for (int s = 0; s < LB; ++s)
                stage64(gB + (size_t)(BN / 2 + s * 64) * K + (size_t)(t + 2) * 64, K, Bb + (BN / 2 + s * 64) * 128, tid);
        }
        if (t + 2 < NT) {
            asm volatile("s_waitcnt vmcnt(4)" ::: "memory");
        } else if (t + 1 < NT) {
            asm volatile("s_waitcnt vmcnt(0)" ::: "memory");
        }
        SBAR;
        if (t + 1 < NT) {
            #pragma unroll
            for (int n = 0; n < NH; ++n)
                #pragma unroll
                for (int kk = 0; kk < 2; ++kk)
                    bf0[n][kk] = ldsRead(BbO, brow0 + n * 16, kk * 64 + cb);
        }
        BARRIER;
        __builtin_amdgcn_s_setprio(1);
        #pragma unroll
        for (int m = 0; m < MH; ++m)
            #pragma unroll
            for (int n = 0; n < NH; ++n)
                #pragma unroll
                for (int kk = 0; kk < 2; ++kk)
                    acc[MH + m][NH + n] = __builtin_amdgcn_mfma_f32_16x16x32_bf16(af[m][kk], bf1[n][kk], acc[MH + m][NH + n], 0, 0, 0);
        __builtin_amdgcn_s_setprio(0);
        SBAR;
        if (t + 1 < NT) {
            #pragma unroll
            for (int m = 0; m < MH; ++m)
                #pragma unroll
                for (int kk = 0; kk < 2; ++kk)
                    af[m][kk] = ldsRead(AbO, arow0 + m * 16, kk * 64 + cb);
        }
        BARRIER;
    }

    // ---- C write: col = lane&15 (+n*16), row = lhi*4 + r (+m*16)
    const int crow0 = bm * BM + wm * (BM / 2) + lhi * 4;
    const int ccol0 = bn * BN + wn * (BN / 4) + l15;
    #pragma unroll
    for (int m = 0; m < MF; ++m) {
        #pragma unroll
        for (int n = 0; n < NF; ++n) {
            int col = ccol0 + n * 16;
            float bv = bias[col];
            #pragma unroll
            for (int r = 0; r < 4; ++r) {
                int row = crow0 + m * 16 + r;
                float v = acc[m][n][r] + bv;
                if (RELU) v = (v > 0.0f) ? v : 0.2f * v;
                C[(size_t)row * Nout + col] = __float2bfloat16(v);
            }
        }
    }
}

// ---------------------------------------------------------------------------
// Epilogue: s/t split, y assembly, per-row log_det
// ---------------------------------------------------------------------------
__global__ __launch_bounds__(256)
void epilogue_kernel(const float* __restrict__ x,
                     const __hip_bfloat16* __restrict__ outb,
                     float* __restrict__ y, float* __restrict__ ld)
{
    const int i = blockIdx.x;
    const int t = threadIdx.x;
    const __hip_bfloat16* orow = outb + (size_t)i * LFULL;
    const float* xrow = x + (size_t)i * LFULL;
    float* yrow = y + (size_t)i * LFULL;

    const int j0 = t * 8;
    u16x8 sv = *(const u16x8*)(orow + j0);
    u16x8 tv = *(const u16x8*)(orow + NHALF + j0);

    float part = 0.0f;
    #pragma unroll
    for (int u = 0; u < 8; u += 2) {
        float4 xv = *(const float4*)(xrow + 2 * (j0 + u));
        float s0 = bf2f(sv[u]),     s1 = bf2f(sv[u + 1]);
        float t0 = bf2f(tv[u]),     t1 = bf2f(tv[u + 1]);
        float a0 = 2.0f * fast_tanh(s0);
        float a1 = 2.0f * fast_tanh(s1);
        part += a0 + a1;
        float4 yv;
        yv.x = xv.x;  yv.y = xv.y * __expf(a0) + t0;
        yv.z = xv.z;  yv.w = xv.w * __expf(a1) + t1;
        *(float4*)(yrow + 2 * (j0 + u)) = yv;
    }

    #pragma unroll
    for (int off = 32; off; off >>= 1) part += __shfl_down(part, off, 64);
    __shared__ float red[4];
    if ((t & 63) == 0) red[t >> 6] = part;
    __syncthreads();
    if (t == 0) ld[i] = red[0] + red[1] + red[2] + red[3];
}

// ---------------------------------------------------------------------------
extern "C" void kernel_launch(void* const* d_in, const int* in_sizes, int n_in,
                              void* d_out, int out_size, void* d_ws, size_t ws_size,
                              hipStream_t stream)
{
    const float* x  = (const float*)d_in[0];
    const float* W1 = (const float*)d_in[1];
    const float* b1 = (const float*)d_in[2];
    const float* W2 = (const float*)d_in[3];
    const float* b2 = (const float*)d_in[4];
    const float* W3 = (const float*)d_in[5];
    const float* b3 = (const float*)d_in[6];

    char* ws = (char*)d_ws;
    const size_t MB = 1u << 20;
    __hip_bfloat16* W3T  = (__hip_bfloat16*)(ws);              // 16 MB: 4096x2048
    __hip_bfloat16* h2   = (__hip_bfloat16*)(ws + 16 * MB);    // 16 MB: 4096x2048
    __hip_bfloat16* xmb  = (__hip_bfloat16*)(ws + 32 * MB);    // 16 MB
    __hip_bfloat16* W1T  = (__hip_bfloat16*)(ws + 48 * MB);    //  8 MB
    __hip_bfloat16* W2T  = (__hip_bfloat16*)(ws + 56 * MB);    //  8 MB
    __hip_bfloat16* h1   = (__hip_bfloat16*)(ws + 64 * MB);    // 16 MB
    __hip_bfloat16* outb = (__hip_bfloat16*)(ws + 32 * MB);    // 32 MB (overlays xmb/W1T/W2T)

    float* y  = (float*)d_out;
    float* ld = y + (size_t)MROWS * LFULL;

    cast_x_kernel<<<4096, 256, 0, stream>>>(x, xmb);
    transpose_cast_kernel<<<dim3(32, 32), 256, 0, stream>>>(W1, W1T, HDIM, HDIM);
    transpose_cast_kernel<<<dim3(32, 32), 256, 0, stream>>>(W2, W2T, HDIM, HDIM);
    transpose_cast_kernel<<<dim3(64, 32), 256, 0, stream>>>(W3, W3T, HDIM, LFULL);

    gemm8p<128, 256, true ><<<dim3(256), dim3(512), 0, stream>>>(xmb, W1T, b1, h1, MROWS, HDIM, HDIM);
    gemm8p<128, 256, true ><<<dim3(256), dim3(512), 0, stream>>>(h1,  W2T, b2, h2, MROWS, HDIM, HDIM);
    gemm8p<256, 256, false><<<dim3(256), dim3(512), 0, stream>>>(h2,  W3T, b3, outb, MROWS, HDIM, LFULL);

    epilogue_kernel<<<4096, 256, 0, stream>>>(x, outb, y, ld);
}

// Round 5
// 206.082 us; speedup vs baseline: 1.2573x; 1.0610x over previous
//
#include <hip/hip_runtime.h>
#include <hip/hip_bf16.h>
#include <stdint.h>

// Problem sizes (fixed)
#define MROWS 4096   // batch B
#define LFULL 4096   // L
#define NHALF 2048   // N = L/2
#define HDIM  2048   // H

typedef __bf16 bf16x8 __attribute__((ext_vector_type(8)));
typedef float  f32x4  __attribute__((ext_vector_type(4)));
typedef unsigned short u16x8 __attribute__((ext_vector_type(8)));

template<int V> struct ICt { static constexpr int value = V; };

__device__ __forceinline__ unsigned short f2bf(float f) {
    __hip_bfloat16 h = __float2bfloat16(f);
    return __builtin_bit_cast(unsigned short, h);
}
__device__ __forceinline__ float bf2f(unsigned short u) {
    return __builtin_bit_cast(float, (uint32_t)u << 16);
}
__device__ __forceinline__ float fast_tanh(float x) {
    float ax = fabsf(x);
    float e  = __expf(-2.0f * ax);
    float t  = (1.0f - e) / (1.0f + e);
    return copysignf(t, x);
}

__device__ __forceinline__ void gload_lds16(const void* g, void* l) {
    __builtin_amdgcn_global_load_lds(
        (const __attribute__((address_space(1))) uint32_t*)g,
        (__attribute__((address_space(3))) uint32_t*)l,
        16, 0, 0);
}

#define SBAR    __builtin_amdgcn_sched_barrier(0)
#define BARRIER do { SBAR; __builtin_amdgcn_s_barrier(); SBAR; } while (0)

// ---------------------------------------------------------------------------
// Cast x even columns -> bf16 x_m (MROWS x NHALF)
// ---------------------------------------------------------------------------
__global__ __launch_bounds__(256)
void cast_x_kernel(const float* __restrict__ x, __hip_bfloat16* __restrict__ xm)
{
    size_t t = (size_t)blockIdx.x * 256 + threadIdx.x;
    size_t r = t >> 8;
    int    c = (int)(t & 255);
    const float4* xp = (const float4*)(x + r * LFULL + (size_t)c * 16);
    float4 a = xp[0], b = xp[1], d = xp[2], e = xp[3];
    u16x8 v;
    v[0] = f2bf(a.x); v[1] = f2bf(a.z);
    v[2] = f2bf(b.x); v[3] = f2bf(b.z);
    v[4] = f2bf(d.x); v[5] = f2bf(d.z);
    v[6] = f2bf(e.x); v[7] = f2bf(e.z);
    *(u16x8*)(xm + r * NHALF + (size_t)c * 8) = v;
}

// ---------------------------------------------------------------------------
// Transpose + cast: W (K x N, f32) -> WT (N x K, bf16)
// ---------------------------------------------------------------------------
__global__ __launch_bounds__(256)
void transpose_cast_kernel(const float* __restrict__ W, __hip_bfloat16* __restrict__ WT,
                           int K, int N)
{
    __shared__ unsigned short lds[64][66];
    const int t  = threadIdx.x;
    const int k0 = blockIdx.y * 64;
    const int n0 = blockIdx.x * 64;

    #pragma unroll
    for (int it = 0; it < 4; ++it) {
        int kl = it * 16 + (t >> 4);
        int nl = (t & 15) * 4;
        float4 v = *(const float4*)(W + (size_t)(k0 + kl) * N + n0 + nl);
        lds[kl][nl + 0] = f2bf(v.x);
        lds[kl][nl + 1] = f2bf(v.y);
        lds[kl][nl + 2] = f2bf(v.z);
        lds[kl][nl + 3] = f2bf(v.w);
    }
    __syncthreads();

    int nl = t >> 2;
    int kc = (t & 3) * 16;
    unsigned short tmp[16];
    #pragma unroll
    for (int j = 0; j < 16; ++j) tmp[j] = lds[kc + j][nl];
    u16x8* dst = (u16x8*)(WT + (size_t)(n0 + nl) * K + k0 + kc);
    dst[0] = *(u16x8*)&tmp[0];
    dst[1] = *(u16x8*)&tmp[8];
}

// ---------------------------------------------------------------------------
// 8-phase GEMM, address-hoisted. A: MxKD bf16 row-major; BT: NOUT x KD bf16.
// 8 waves (2M x 4N). K-tile=64. LDS layout [Abuf0|Abuf1|Bbuf0|Bbuf1].
// K-loop unrolled x2 so buffer select is compile-time: all ds_read addresses
// are 4 invariant VGPR bases + immediate offsets (zero per-tile VALU).
// Phases per tile t: p0 {read aLO,bLO; stage A0(t+1); mfma q00}
//                    p1 {read bHI;     stage A1(t+1); mfma q01}
//                    p2 {read aHI;     stage B0(t+2); mfma q10}
//                    p3 {             stage B1(t+2); mfma q11; vmcnt(4)}
// vmcnt(4) leaves B(t+2) in flight, guarantees A(t+1),B(t+1) landed; the
// tile-end barrier makes that visible to all waves before t+1's reads.
// ---------------------------------------------------------------------------
template<int BM, int BN, int KD, int NOUT, bool RELU>
__global__ __launch_bounds__(512, 2)
void gemm8p(const __hip_bfloat16* __restrict__ A,
            const __hip_bfloat16* __restrict__ BT,
            const float* __restrict__ bias,
            __hip_bfloat16* __restrict__ C)
{
    constexpr int MF = BM / 32, NF = BN / 64, MH = MF / 2, NH = NF / 2;
    constexpr int LA = BM / 128, LB = BN / 128;
    constexpr int NT = KD / 64;
    constexpr int ABYTES = BM * 128, BBYTES = BN * 128;
    constexpr int BBASE = 2 * ABYTES;
    __shared__ __align__(1024) char lds[2 * ABYTES + 2 * BBYTES];

    const int tid  = threadIdx.x;
    const int wave = tid >> 6, lane = tid & 63;
    const int wm = wave >> 2, wn = wave & 3;
    const int l15 = lane & 15, lhi = lane >> 4;

    // XCD-aware bijective swizzle (grid multiple of 8)
    const int nwg = gridDim.x;
    const int bid = blockIdx.x;
    const int wg  = (bid & 7) * (nwg >> 3) + (bid >> 3);
    constexpr int NBN = NOUT / BN;
    const int bm = wg / NBN, bn = wg % NBN;

    const __hip_bfloat16* gA = A  + (size_t)(bm * BM) * KD;
    const __hip_bfloat16* gB = BT + (size_t)(bn * BN) * KD;

    // staging thread mapping: row=tid>>3, 16B chunk=tid&7; source chunk
    // XOR-swizzled by row&7 (pairs with swizzled ds_read below)
    const int srow = tid >> 3;
    const int scol = ((tid & 7) ^ (srow & 7)) * 8;   // elements
    char* sd = lds + srow * 128 + (tid & 7) * 16;    // linear LDS dest

    const __hip_bfloat16* pA = gA + (size_t)srow * KD + scol;
    const __hip_bfloat16* pB = gB + (size_t)srow * KD + scol;

    // ---- prologue: B(0) -> Bbuf0, A(0) -> Abuf0, B(1) -> Bbuf1
    #pragma unroll
    for (int s = 0; s < LB; ++s) gload_lds16(pB + (size_t)(s * 64) * KD,            sd + BBASE + s * 8192);
    #pragma unroll
    for (int s = 0; s < LB; ++s) gload_lds16(pB + (size_t)(BN/2 + s * 64) * KD,     sd + BBASE + (BN/2) * 128 + s * 8192);
    #pragma unroll
    for (int s = 0; s < LA; ++s) gload_lds16(pA + (size_t)(s * 64) * KD,            sd + s * 8192);
    #pragma unroll
    for (int s = 0; s < LA; ++s) gload_lds16(pA + (size_t)(BM/2 + s * 64) * KD,     sd + (BM/2) * 128 + s * 8192);
    #pragma unroll
    for (int s = 0; s < LB; ++s) gload_lds16(pB + 64 + (size_t)(s * 64) * KD,       sd + BBASE + BBYTES + s * 8192);
    #pragma unroll
    for (int s = 0; s < LB; ++s) gload_lds16(pB + 64 + (size_t)(BN/2 + s * 64) * KD, sd + BBASE + BBYTES + (BN/2) * 128 + s * 8192);
    pA += 64; pB += 128;
    asm volatile("s_waitcnt vmcnt(4)" ::: "memory");
    BARRIER;

    // ---- invariant per-lane LDS read bases (swizzle folds to (l15&7)<<4)
    const int arow0 = wm * (BM / 2) + l15;
    const int brow0 = wn * (BN / 4) + l15;
    const int swz   = (l15 & 7) << 4;
    const int colX[2] = { (lhi * 16) ^ swz, (64 + lhi * 16) ^ swz };
    const char* rA = lds + arow0 * 128;
    const char* rB = lds + BBASE + brow0 * 128;

    bf16x8 af[MH][2], bf0[NH][2], bf1[NH][2];
    f32x4 acc[MF][NF] = {};

    auto body = [&](int t, auto bufc) {
        constexpr int BUF   = decltype(bufc)::value;
        constexpr int ABUF  = BUF * ABYTES;
        constexpr int ABUFo = (BUF ^ 1) * ABYTES;
        constexpr int BBUF  = BUF * BBYTES;

        // ---- phase 0: read aLO,bLO; stage A0(t+1); MFMA q(0,0)
        #pragma unroll
        for (int m = 0; m < MH; ++m)
            #pragma unroll
            for (int kk = 0; kk < 2; ++kk)
                af[m][kk] = *(const bf16x8*)(rA + colX[kk] + (ABUF + m * 2048));
        #pragma unroll
        for (int n = 0; n < NH; ++n)
            #pragma unroll
            for (int kk = 0; kk < 2; ++kk)
                bf0[n][kk] = *(const bf16x8*)(rB + colX[kk] + (BBUF + n * 2048));
        if (t + 1 < NT) {
            #pragma unroll
            for (int s = 0; s < LA; ++s)
                gload_lds16(pA + (size_t)(s * 64) * KD, sd + ABUFo + s * 8192);
        }
        BARRIER;
        __builtin_amdgcn_s_setprio(1);
        #pragma unroll
        for (int kk = 0; kk < 2; ++kk)
            #pragma unroll
            for (int m = 0; m < MH; ++m)
                #pragma unroll
                for (int n = 0; n < NH; ++n)
                    acc[m][n] = __builtin_amdgcn_mfma_f32_16x16x32_bf16(af[m][kk], bf0[n][kk], acc[m][n], 0, 0, 0);
        __builtin_amdgcn_s_setprio(0);
        BARRIER;

        // ---- phase 1: read bHI; stage A1(t+1); MFMA q(0,1)
        #pragma unroll
        for (int n = 0; n < NH; ++n)
            #pragma unroll
            for (int kk = 0; kk < 2; ++kk)
                bf1[n][kk] = *(const bf16x8*)(rB + colX[kk] + (BBUF + (NH + n) * 2048));
        if (t + 1 < NT) {
            #pragma unroll
            for (int s = 0; s < LA; ++s)
                gload_lds16(pA + (size_t)(BM/2 + s * 64) * KD, sd + ABUFo + (BM/2) * 128 + s * 8192);
        }
        BARRIER;
        __builtin_amdgcn_s_setprio(1);
        #pragma unroll
        for (int kk = 0; kk < 2; ++kk)
            #pragma unroll
            for (int m = 0; m < MH; ++m)
                #pragma unroll
                for (int n = 0; n < NH; ++n)
                    acc[m][NH + n] = __builtin_amdgcn_mfma_f32_16x16x32_bf16(af[m][kk], bf1[n][kk], acc[m][NH + n], 0, 0, 0);
        __builtin_amdgcn_s_setprio(0);
        BARRIER;

        // ---- phase 2: read aHI; stage B0(t+2); MFMA q(1,0)
        #pragma unroll
        for (int m = 0; m < MH; ++m)
            #pragma unroll
            for (int kk = 0; kk < 2; ++kk)
                af[m][kk] = *(const bf16x8*)(rA + colX[kk] + (ABUF + (MH + m) * 2048));
        if (t + 2 < NT) {
            #pragma unroll
            for (int s = 0; s < LB; ++s)
                gload_lds16(pB + (size_t)(s * 64) * KD, sd + BBASE + BBUF + s * 8192);
        }
        BARRIER;
        __builtin_amdgcn_s_setprio(1);
        #pragma unroll
        for (int kk = 0; kk < 2; ++kk)
            #pragma unroll
            for (int m = 0; m < MH; ++m)
                #pragma unroll
                for (int n = 0; n < NH; ++n)
                    acc[MH + m][n] = __builtin_amdgcn_mfma_f32_16x16x32_bf16(af[m][kk], bf0[n][kk], acc[MH + m][n], 0, 0, 0);
        __builtin_amdgcn_s_setprio(0);
        BARRIER;

        // ---- phase 3: stage B1(t+2); MFMA q(1,1); vmcnt; barrier
        if (t + 2 < NT) {
            #pragma unroll
            for (int s = 0; s < LB; ++s)
                gload_lds16(pB + (size_t)(BN/2 + s * 64) * KD, sd + BBASE + BBUF + (BN/2) * 128 + s * 8192);
        }
        BARRIER;
        __builtin_amdgcn_s_setprio(1);
        #pragma unroll
        for (int kk = 0; kk < 2; ++kk)
            #pragma unroll
            for (int m = 0; m < MH; ++m)
                #pragma unroll
                for (int n = 0; n < NH; ++n)
                    acc[MH + m][NH + n] = __builtin_amdgcn_mfma_f32_16x16x32_bf16(af[m][kk], bf1[n][kk], acc[MH + m][NH + n], 0, 0, 0);
        __builtin_amdgcn_s_setprio(0);
        if (t + 2 < NT) {
            asm volatile("s_waitcnt vmcnt(4)" ::: "memory");
        } else if (t + 1 < NT) {
            asm volatile("s_waitcnt vmcnt(0)" ::: "memory");
        }
        BARRIER;
        pA += 64; pB += 64;
    };

    for (int tt = 0; tt < NT; tt += 2) {
        body(tt,     ICt<0>{});
        body(tt + 1, ICt<1>{});
    }

    // ---- C write: col = lane&15 (+n*16), row = lhi*4 + r (+m*16)
    const int crow0 = bm * BM + wm * (BM / 2) + lhi * 4;
    const int ccol0 = bn * BN + wn * (BN / 4) + l15;
    #pragma unroll
    for (int m = 0; m < MF; ++m) {
        #pragma unroll
        for (int n = 0; n < NF; ++n) {
            int col = ccol0 + n * 16;
            float bv = bias[col];
            #pragma unroll
            for (int r = 0; r < 4; ++r) {
                int row = crow0 + m * 16 + r;
                float v = acc[m][n][r] + bv;
                if (RELU) v = (v > 0.0f) ? v : 0.2f * v;
                C[(size_t)row * NOUT + col] = __float2bfloat16(v);
            }
        }
    }
}

// ---------------------------------------------------------------------------
// Epilogue: s/t split, y assembly, per-row log_det
// ---------------------------------------------------------------------------
__global__ __launch_bounds__(256)
void epilogue_kernel(const float* __restrict__ x,
                     const __hip_bfloat16* __restrict__ outb,
                     float* __restrict__ y, float* __restrict__ ld)
{
    const int i = blockIdx.x;
    const int t = threadIdx.x;
    const __hip_bfloat16* orow = outb + (size_t)i * LFULL;
    const float* xrow = x + (size_t)i * LFULL;
    float* yrow = y + (size_t)i * LFULL;

    const int j0 = t * 8;
    u16x8 sv = *(const u16x8*)(orow + j0);
    u16x8 tv = *(const u16x8*)(orow + NHALF + j0);

    float part = 0.0f;
    #pragma unroll
    for (int u = 0; u < 8; u += 2) {
        float4 xv = *(const float4*)(xrow + 2 * (j0 + u));
        float s0 = bf2f(sv[u]),     s1 = bf2f(sv[u + 1]);
        float t0 = bf2f(tv[u]),     t1 = bf2f(tv[u + 1]);
        float a0 = 2.0f * fast_tanh(s0);
        float a1 = 2.0f * fast_tanh(s1);
        part += a0 + a1;
        float4 yv;
        yv.x = xv.x;  yv.y = xv.y * __expf(a0) + t0;
        yv.z = xv.z;  yv.w = xv.w * __expf(a1) + t1;
        *(float4*)(yrow + 2 * (j0 + u)) = yv;
    }

    #pragma unroll
    for (int off = 32; off; off >>= 1) part += __shfl_down(part, off, 64);
    __shared__ float red[4];
    if ((t & 63) == 0) red[t >> 6] = part;
    __syncthreads();
    if (t == 0) ld[i] = red[0] + red[1] + red[2] + red[3];
}

// ---------------------------------------------------------------------------
extern "C" void kernel_launch(void* const* d_in, const int* in_sizes, int n_in,
                              void* d_out, int out_size, void* d_ws, size_t ws_size,
                              hipStream_t stream)
{
    const float* x  = (const float*)d_in[0];
    const float* W1 = (const float*)d_in[1];
    const float* b1 = (const float*)d_in[2];
    const float* W2 = (const float*)d_in[3];
    const float* b2 = (const float*)d_in[4];
    const float* W3 = (const float*)d_in[5];
    const float* b3 = (const float*)d_in[6];

    char* ws = (char*)d_ws;
    const size_t MB = 1u << 20;
    __hip_bfloat16* W3T  = (__hip_bfloat16*)(ws);              // 16 MB: 4096x2048
    __hip_bfloat16* h2   = (__hip_bfloat16*)(ws + 16 * MB);    // 16 MB: 4096x2048
    __hip_bfloat16* xmb  = (__hip_bfloat16*)(ws + 32 * MB);    // 16 MB
    __hip_bfloat16* W1T  = (__hip_bfloat16*)(ws + 48 * MB);    //  8 MB
    __hip_bfloat16* W2T  = (__hip_bfloat16*)(ws + 56 * MB);    //  8 MB
    __hip_bfloat16* h1   = (__hip_bfloat16*)(ws + 64 * MB);    // 16 MB
    __hip_bfloat16* outb = (__hip_bfloat16*)(ws + 32 * MB);    // 32 MB (overlays xmb/W1T/W2T)

    float* y  = (float*)d_out;
    float* ld = y + (size_t)MROWS * LFULL;

    cast_x_kernel<<<4096, 256, 0, stream>>>(x, xmb);
    transpose_cast_kernel<<<dim3(32, 32), 256, 0, stream>>>(W1, W1T, HDIM, HDIM);
    transpose_cast_kernel<<<dim3(32, 32), 256, 0, stream>>>(W2, W2T, HDIM, HDIM);
    transpose_cast_kernel<<<dim3(64, 32), 256, 0, stream>>>(W3, W3T, HDIM, LFULL);

    gemm8p<128, 256, 2048, 2048, true ><<<dim3(256), dim3(512), 0, stream>>>(xmb, W1T, b1, h1);
    gemm8p<128, 256, 2048, 2048, true ><<<dim3(256), dim3(512), 0, stream>>>(h1,  W2T, b2, h2);
    gemm8p<256, 256, 2048, 4096, false><<<dim3(256), dim3(512), 0, stream>>>(h2,  W3T, b3, outb);

    epilogue_kernel<<<4096, 256, 0, stream>>>(x, outb, y, ld);
}

// Round 6
// 197.970 us; speedup vs baseline: 1.3088x; 1.0410x over previous
//
#include <hip/hip_runtime.h>
#include <hip/hip_bf16.h>
#include <stdint.h>

// Problem sizes (fixed)
#define MROWS 4096   // batch B
#define LFULL 4096   // L
#define NHALF 2048   // N = L/2
#define HDIM  2048   // H

typedef __bf16 bf16x8 __attribute__((ext_vector_type(8)));
typedef float  f32x4  __attribute__((ext_vector_type(4)));
typedef unsigned short u16x8 __attribute__((ext_vector_type(8)));

template<int V> struct ICt { static constexpr int value = V; };

__device__ __forceinline__ unsigned short f2bf(float f) {
    __hip_bfloat16 h = __float2bfloat16(f);
    return __builtin_bit_cast(unsigned short, h);
}
__device__ __forceinline__ float bf2f(unsigned short u) {
    return __builtin_bit_cast(float, (uint32_t)u << 16);
}
__device__ __forceinline__ float fast_tanh(float x) {
    float ax = fabsf(x);
    float e  = __expf(-2.0f * ax);
    float t  = (1.0f - e) / (1.0f + e);
    return copysignf(t, x);
}

__device__ __forceinline__ void gload_lds16(const void* g, void* l) {
    __builtin_amdgcn_global_load_lds(
        (const __attribute__((address_space(1))) uint32_t*)g,
        (__attribute__((address_space(3))) uint32_t*)l,
        16, 0, 0);
}

// ---------------------------------------------------------------------------
// Cast x even columns -> bf16 x_m (MROWS x NHALF)
// ---------------------------------------------------------------------------
__global__ __launch_bounds__(256)
void cast_x_kernel(const float* __restrict__ x, __hip_bfloat16* __restrict__ xm)
{
    size_t t = (size_t)blockIdx.x * 256 + threadIdx.x;
    size_t r = t >> 8;
    int    c = (int)(t & 255);
    const float4* xp = (const float4*)(x + r * LFULL + (size_t)c * 16);
    float4 a = xp[0], b = xp[1], d = xp[2], e = xp[3];
    u16x8 v;
    v[0] = f2bf(a.x); v[1] = f2bf(a.z);
    v[2] = f2bf(b.x); v[3] = f2bf(b.z);
    v[4] = f2bf(d.x); v[5] = f2bf(d.z);
    v[6] = f2bf(e.x); v[7] = f2bf(e.z);
    *(u16x8*)(xm + r * NHALF + (size_t)c * 8) = v;
}

// ---------------------------------------------------------------------------
// Transpose + cast: W (K x N, f32) -> WT (N x K, bf16)
// ---------------------------------------------------------------------------
__global__ __launch_bounds__(256)
void transpose_cast_kernel(const float* __restrict__ W, __hip_bfloat16* __restrict__ WT,
                           int K, int N)
{
    __shared__ unsigned short lds[64][66];
    const int t  = threadIdx.x;
    const int k0 = blockIdx.y * 64;
    const int n0 = blockIdx.x * 64;

    #pragma unroll
    for (int it = 0; it < 4; ++it) {
        int kl = it * 16 + (t >> 4);
        int nl = (t & 15) * 4;
        float4 v = *(const float4*)(W + (size_t)(k0 + kl) * N + n0 + nl);
        lds[kl][nl + 0] = f2bf(v.x);
        lds[kl][nl + 1] = f2bf(v.y);
        lds[kl][nl + 2] = f2bf(v.z);
        lds[kl][nl + 3] = f2bf(v.w);
    }
    __syncthreads();

    int nl = t >> 2;
    int kc = (t & 3) * 16;
    unsigned short tmp[16];
    #pragma unroll
    for (int j = 0; j < 16; ++j) tmp[j] = lds[kc + j][nl];
    u16x8* dst = (u16x8*)(WT + (size_t)(n0 + nl) * K + k0 + kc);
    dst[0] = *(u16x8*)&tmp[0];
    dst[1] = *(u16x8*)&tmp[8];
}

// ---------------------------------------------------------------------------
// 8-phase GEMM, counted-wait pipelined. A: MxKD bf16 row-major; BT: NOUTxKD.
// 8 waves (2M x 4N). K-tile=64. LDS [Abuf0|Abuf1|Bbuf0|Bbuf1], x2 K-unroll
// so buffer selects are compile-time. ds_reads are issued one phase AHEAD of
// their consuming MFMA (placed post-MFMA/post-barrier so scheduling regions
// pin them); the compiler then emits COUNTED lgkmcnt waits -> LDS drain
// overlaps MFMA clusters. No sched_barrier (m141: pinning defeats scheduler).
// Quad order q00,q01,q10,q11; per tile:
//   P0: stage A0(t+1); MFMA q00(aLO,bLO);  read bHI(t)      ; bar
//   P1: stage A1(t+1); MFMA q01(aLO,bHI);  read aHI(t)->af  ; bar
//   P2: stage B0(t+2); MFMA q10(aHI,bLO)                    ; bar
//   P3: stage B1(t+2); vmcnt(4); bar(tile boundary);
//       read bLO(t+1)->bf0; MFMA q11(aHI,bHI); read aLO(t+1)->af
// vmcnt(4) keeps only B(t+2)'s 4 stage-calls in flight: A(t+1),B(t+1) landed
// for all waves after the P3 barrier.
// ---------------------------------------------------------------------------
template<int BM, int BN, int KD, int NOUT, bool RELU>
__global__ __launch_bounds__(512, 2)
void gemm8p(const __hip_bfloat16* __restrict__ A,
            const __hip_bfloat16* __restrict__ BT,
            const float* __restrict__ bias,
            __hip_bfloat16* __restrict__ C)
{
    constexpr int MF = BM / 32, NF = BN / 64, MH = MF / 2, NH = NF / 2;
    constexpr int LA = BM / 128, LB = BN / 128;
    constexpr int NT = KD / 64;
    constexpr int ABYTES = BM * 128, BBYTES = BN * 128;
    constexpr int BBASE = 2 * ABYTES;
    __shared__ __align__(1024) char lds[2 * ABYTES + 2 * BBYTES];

    const int tid  = threadIdx.x;
    const int wave = tid >> 6, lane = tid & 63;
    const int wm = wave >> 2, wn = wave & 3;
    const int l15 = lane & 15, lhi = lane >> 4;

    // XCD-aware bijective swizzle (grid multiple of 8)
    const int nwg = gridDim.x;
    const int bid = blockIdx.x;
    const int wg  = (bid & 7) * (nwg >> 3) + (bid >> 3);
    constexpr int NBN = NOUT / BN;
    const int bm = wg / NBN, bn = wg % NBN;

    const __hip_bfloat16* gA = A  + (size_t)(bm * BM) * KD;
    const __hip_bfloat16* gB = BT + (size_t)(bn * BN) * KD;

    // staging: row=tid>>3, 16B chunk=tid&7; source chunk XOR-swizzled by row&7
    const int srow = tid >> 3;
    const int scol = ((tid & 7) ^ (srow & 7)) * 8;   // elements
    char* sd = lds + srow * 128 + (tid & 7) * 16;    // linear LDS dest

    const __hip_bfloat16* pA = gA + (size_t)srow * KD + scol;
    const __hip_bfloat16* pB = gB + (size_t)srow * KD + scol;

    // ---- prologue: B(0)->Bbuf0, A(0)->Abuf0, B(1)->Bbuf1
    #pragma unroll
    for (int s = 0; s < LB; ++s) gload_lds16(pB + (size_t)(s * 64) * KD,             sd + BBASE + s * 8192);
    #pragma unroll
    for (int s = 0; s < LB; ++s) gload_lds16(pB + (size_t)(BN/2 + s * 64) * KD,      sd + BBASE + (BN/2) * 128 + s * 8192);
    #pragma unroll
    for (int s = 0; s < LA; ++s) gload_lds16(pA + (size_t)(s * 64) * KD,             sd + s * 8192);
    #pragma unroll
    for (int s = 0; s < LA; ++s) gload_lds16(pA + (size_t)(BM/2 + s * 64) * KD,      sd + (BM/2) * 128 + s * 8192);
    #pragma unroll
    for (int s = 0; s < LB; ++s) gload_lds16(pB + 64 + (size_t)(s * 64) * KD,        sd + BBASE + BBYTES + s * 8192);
    #pragma unroll
    for (int s = 0; s < LB; ++s) gload_lds16(pB + 64 + (size_t)(BN/2 + s * 64) * KD, sd + BBASE + BBYTES + (BN/2) * 128 + s * 8192);
    pA += 64; pB += 128;
    asm volatile("s_waitcnt vmcnt(4)" ::: "memory");
    __builtin_amdgcn_s_barrier();

    // ---- invariant per-lane LDS read bases (swizzle folds to (l15&7)<<4)
    const int arow0 = wm * (BM / 2) + l15;
    const int brow0 = wn * (BN / 4) + l15;
    const int swz   = (l15 & 7) << 4;
    const int colX[2] = { (lhi * 16) ^ swz, (64 + lhi * 16) ^ swz };
    const char* rA = lds + arow0 * 128;
    const char* rB = lds + brow0 * 128;

    bf16x8 af[MH][2], bf0[NH][2], bf1[NH][2];
    f32x4 acc[MF][NF] = {};

    // pre-read aLO(0), bLO(0)
    #pragma unroll
    for (int m = 0; m < MH; ++m)
        #pragma unroll
        for (int kk = 0; kk < 2; ++kk)
            af[m][kk] = *(const bf16x8*)(rA + colX[kk] + m * 2048);
    #pragma unroll
    for (int n = 0; n < NH; ++n)
        #pragma unroll
        for (int kk = 0; kk < 2; ++kk)
            bf0[n][kk] = *(const bf16x8*)(rB + colX[kk] + (BBASE + n * 2048));

    auto body = [&](int t, auto bufc) {
        constexpr int BUF   = decltype(bufc)::value;
        constexpr int ABUF  = BUF * ABYTES;
        constexpr int ABUFo = (BUF ^ 1) * ABYTES;
        constexpr int BBUF  = BBASE + BUF * BBYTES;
        constexpr int BBUFo = BBASE + (BUF ^ 1) * BBYTES;

        // ---- P0: stage A0(t+1); MFMA q00; read bHI(t)
        if (t + 1 < NT) {
            #pragma unroll
            for (int s = 0; s < LA; ++s)
                gload_lds16(pA + (size_t)(s * 64) * KD, sd + ABUFo + s * 8192);
        }
        __builtin_amdgcn_s_setprio(1);
        #pragma unroll
        for (int kk = 0; kk < 2; ++kk)
            #pragma unroll
            for (int m = 0; m < MH; ++m)
                #pragma unroll
                for (int n = 0; n < NH; ++n)
                    acc[m][n] = __builtin_amdgcn_mfma_f32_16x16x32_bf16(af[m][kk], bf0[n][kk], acc[m][n], 0, 0, 0);
        __builtin_amdgcn_s_setprio(0);
        #pragma unroll
        for (int n = 0; n < NH; ++n)
            #pragma unroll
            for (int kk = 0; kk < 2; ++kk)
                bf1[n][kk] = *(const bf16x8*)(rB + colX[kk] + (BBUF + (NH + n) * 2048));
        __builtin_amdgcn_s_barrier();

        // ---- P1: stage A1(t+1); MFMA q01; read aHI(t)
        if (t + 1 < NT) {
            #pragma unroll
            for (int s = 0; s < LA; ++s)
                gload_lds16(pA + (size_t)(BM/2 + s * 64) * KD, sd + ABUFo + (BM/2) * 128 + s * 8192);
        }
        __builtin_amdgcn_s_setprio(1);
        #pragma unroll
        for (int kk = 0; kk < 2; ++kk)
            #pragma unroll
            for (int m = 0; m < MH; ++m)
                #pragma unroll
                for (int n = 0; n < NH; ++n)
                    acc[m][NH + n] = __builtin_amdgcn_mfma_f32_16x16x32_bf16(af[m][kk], bf1[n][kk], acc[m][NH + n], 0, 0, 0);
        __builtin_amdgcn_s_setprio(0);
        #pragma unroll
        for (int m = 0; m < MH; ++m)
            #pragma unroll
            for (int kk = 0; kk < 2; ++kk)
                af[m][kk] = *(const bf16x8*)(rA + colX[kk] + (ABUF + (MH + m) * 2048));
        __builtin_amdgcn_s_barrier();

        // ---- P2: stage B0(t+2); MFMA q10
        if (t + 2 < NT) {
            #pragma unroll
            for (int s = 0; s < LB; ++s)
                gload_lds16(pB + (size_t)(s * 64) * KD, sd + BBUF + s * 8192);
        }
        __builtin_amdgcn_s_setprio(1);
        #pragma unroll
        for (int kk = 0; kk < 2; ++kk)
            #pragma unroll
            for (int m = 0; m < MH; ++m)
                #pragma unroll
                for (int n = 0; n < NH; ++n)
                    acc[MH + m][n] = __builtin_amdgcn_mfma_f32_16x16x32_bf16(af[m][kk], bf0[n][kk], acc[MH + m][n], 0, 0, 0);
        __builtin_amdgcn_s_setprio(0);
        __builtin_amdgcn_s_barrier();

        // ---- P3: stage B1(t+2); vmcnt; tile-boundary barrier;
        //          read bLO(t+1); MFMA q11; read aLO(t+1)
        if (t + 2 < NT) {
            #pragma unroll
            for (int s = 0; s < LB; ++s)
                gload_lds16(pB + (size_t)(BN/2 + s * 64) * KD, sd + BBUF + (BN/2) * 128 + s * 8192);
            asm volatile("s_waitcnt vmcnt(4)" ::: "memory");
        } else {
            asm volatile("s_waitcnt vmcnt(0)" ::: "memory");
        }
        __builtin_amdgcn_s_barrier();
        if (t + 1 < NT) {
            #pragma unroll
            for (int n = 0; n < NH; ++n)
                #pragma unroll
                for (int kk = 0; kk < 2; ++kk)
                    bf0[n][kk] = *(const bf16x8*)(rB + colX[kk] + (BBUFo + n * 2048));
        }
        __builtin_amdgcn_s_setprio(1);
        #pragma unroll
        for (int kk = 0; kk < 2; ++kk)
            #pragma unroll
            for (int m = 0; m < MH; ++m)
                #pragma unroll
                for (int n = 0; n < NH; ++n)
                    acc[MH + m][NH + n] = __builtin_amdgcn_mfma_f32_16x16x32_bf16(af[m][kk], bf1[n][kk], acc[MH + m][NH + n], 0, 0, 0);
        __builtin_amdgcn_s_setprio(0);
        if (t + 1 < NT) {
            #pragma unroll
            for (int m = 0; m < MH; ++m)
                #pragma unroll
                for (int kk = 0; kk < 2; ++kk)
                    af[m][kk] = *(const bf16x8*)(rA + colX[kk] + (ABUFo + m * 2048));
        }
        pA += 64; pB += 64;
    };

    for (int tt = 0; tt < NT; tt += 2) {
        body(tt,     ICt<0>{});
        body(tt + 1, ICt<1>{});
    }

    // ---- C write: col = lane&15 (+n*16), row = lhi*4 + r (+m*16)
    const int crow0 = bm * BM + wm * (BM / 2) + lhi * 4;
    const int ccol0 = bn * BN + wn * (BN / 4) + l15;
    #pragma unroll
    for (int m = 0; m < MF; ++m) {
        #pragma unroll
        for (int n = 0; n < NF; ++n) {
            int col = ccol0 + n * 16;
            float bv = bias[col];
            #pragma unroll
            for (int r = 0; r < 4; ++r) {
                int row = crow0 + m * 16 + r;
                float v = acc[m][n][r] + bv;
                if (RELU) v = (v > 0.0f) ? v : 0.2f * v;
                C[(size_t)row * NOUT + col] = __float2bfloat16(v);
            }
        }
    }
}

// ---------------------------------------------------------------------------
// Epilogue: s/t split, y assembly, per-row log_det
// ---------------------------------------------------------------------------
__global__ __launch_bounds__(256)
void epilogue_kernel(const float* __restrict__ x,
                     const __hip_bfloat16* __restrict__ outb,
                     float* __restrict__ y, float* __restrict__ ld)
{
    const int i = blockIdx.x;
    const int t = threadIdx.x;
    const __hip_bfloat16* orow = outb + (size_t)i * LFULL;
    const float* xrow = x + (size_t)i * LFULL;
    float* yrow = y + (size_t)i * LFULL;

    const int j0 = t * 8;
    u16x8 sv = *(const u16x8*)(orow + j0);
    u16x8 tv = *(const u16x8*)(orow + NHALF + j0);

    float part = 0.0f;
    #pragma unroll
    for (int u = 0; u < 8; u += 2) {
        float4 xv = *(const float4*)(xrow + 2 * (j0 + u));
        float s0 = bf2f(sv[u]),     s1 = bf2f(sv[u + 1]);
        float t0 = bf2f(tv[u]),     t1 = bf2f(tv[u + 1]);
        float a0 = 2.0f * fast_tanh(s0);
        float a1 = 2.0f * fast_tanh(s1);
        part += a0 + a1;
        float4 yv;
        yv.x = xv.x;  yv.y = xv.y * __expf(a0) + t0;
        yv.z = xv.z;  yv.w = xv.w * __expf(a1) + t1;
        *(float4*)(yrow + 2 * (j0 + u)) = yv;
    }

    #pragma unroll
    for (int off = 32; off; off >>= 1) part += __shfl_down(part, off, 64);
    __shared__ float red[4];
    if ((t & 63) == 0) red[t >> 6] = part;
    __syncthreads();
    if (t == 0) ld[i] = red[0] + red[1] + red[2] + red[3];
}

// ---------------------------------------------------------------------------
extern "C" void kernel_launch(void* const* d_in, const int* in_sizes, int n_in,
                              void* d_out, int out_size, void* d_ws, size_t ws_size,
                              hipStream_t stream)
{
    const float* x  = (const float*)d_in[0];
    const float* W1 = (const float*)d_in[1];
    const float* b1 = (const float*)d_in[2];
    const float* W2 = (const float*)d_in[3];
    const float* b2 = (const float*)d_in[4];
    const float* W3 = (const float*)d_in[5];
    const float* b3 = (const float*)d_in[6];

    char* ws = (char*)d_ws;
    const size_t MB = 1u << 20;
    __hip_bfloat16* W3T  = (__hip_bfloat16*)(ws);              // 16 MB: 4096x2048
    __hip_bfloat16* h2   = (__hip_bfloat16*)(ws + 16 * MB);    // 16 MB: 4096x2048
    __hip_bfloat16* xmb  = (__hip_bfloat16*)(ws + 32 * MB);    // 16 MB
    __hip_bfloat16* W1T  = (__hip_bfloat16*)(ws + 48 * MB);    //  8 MB
    __hip_bfloat16* W2T  = (__hip_bfloat16*)(ws + 56 * MB);    //  8 MB
    __hip_bfloat16* h1   = (__hip_bfloat16*)(ws + 64 * MB);    // 16 MB
    __hip_bfloat16* outb = (__hip_bfloat16*)(ws + 32 * MB);    // 32 MB (overlays xmb/W1T/W2T)

    float* y  = (float*)d_out;
    float* ld = y + (size_t)MROWS * LFULL;

    cast_x_kernel<<<4096, 256, 0, stream>>>(x, xmb);
    transpose_cast_kernel<<<dim3(32, 32), 256, 0, stream>>>(W1, W1T, HDIM, HDIM);
    transpose_cast_kernel<<<dim3(32, 32), 256, 0, stream>>>(W2, W2T, HDIM, HDIM);
    transpose_cast_kernel<<<dim3(64, 32), 256, 0, stream>>>(W3, W3T, HDIM, LFULL);

    gemm8p<128, 256, 2048, 2048, true ><<<dim3(256), dim3(512), 0, stream>>>(xmb, W1T, b1, h1);
    gemm8p<128, 256, 2048, 2048, true ><<<dim3(256), dim3(512), 0, stream>>>(h1,  W2T, b2, h2);
    gemm8p<256, 256, 2048, 4096, false><<<dim3(256), dim3(512), 0, stream>>>(h2,  W3T, b3, outb);

    epilogue_kernel<<<4096, 256, 0, stream>>>(x, outb, y, ld);
}